// Round 1
// baseline (200.676 us; speedup 1.0000x reference)
//
#include <hip/hip_runtime.h>

// Problem constants: B=4, TQ=512, TP=512, D=256
#define NB  4
#define TQS 512
#define TPS 512
#define DD  256

// tanh(x) = 1 - 2/(exp(2x)+1); exp via v_exp_f32 (2^y), rcp via v_rcp_f32.
// Saturates correctly for |x| large (e->inf => 1; e->0 => -1).
__device__ __forceinline__ float fast_tanh(float x) {
    float e = __builtin_amdgcn_exp2f(x * 2.885390081777927f); // exp(2x)
    float r = __builtin_amdgcn_rcpf(e + 1.0f);
    return __builtin_fmaf(-2.0f, r, 1.0f);
}

// Generic row-major fp32 GEMM: C[M,N] = A[M,K] @ B[K,N], batched over grid.z.
// If lvec != nullptr, each B row k is scaled by 1/lvec[bz*sL + k]
// (folds the softmax denominator into the final contraction).
// Requires M%64==0, N%64==0, K%16==0. 256 threads, 64x64 tile, 4x4 per thread.
__global__ __launch_bounds__(256) void gemm_kernel(
    const float* __restrict__ A, const float* __restrict__ B, float* __restrict__ C,
    int M, int N, int K, long sA, long sB, long sC,
    const float* __restrict__ lvec, int sL)
{
    const int bz = blockIdx.z;
    A += bz * sA; B += bz * sB; C += bz * sC;

    __shared__ float As[16][68];   // As[k][m] (transposed), row stride 272B (16B aligned)
    __shared__ float Bs[16][68];   // Bs[k][n]

    const int t  = threadIdx.x;
    const int tx = t & 15, ty = t >> 4;
    const int m0 = blockIdx.y * 64, n0 = blockIdx.x * 64;
    const int a_row = t >> 2,  a_c4 = (t & 3) * 4;   // A tile: 64 rows x 16 k, one float4/thread
    const int b_row = t >> 4,  b_c4 = (t & 15) * 4;  // B tile: 16 rows x 64 n, one float4/thread

    float acc[4][4] = {};

    for (int k0 = 0; k0 < K; k0 += 16) {
        float4 av = *(const float4*)(A + (long)(m0 + a_row) * K + k0 + a_c4);
        float4 bv = *(const float4*)(B + (long)(k0 + b_row) * N + n0 + b_c4);
        if (lvec) {
            float s = __builtin_amdgcn_rcpf(lvec[bz * sL + k0 + b_row]);
            bv.x *= s; bv.y *= s; bv.z *= s; bv.w *= s;
        }
        As[a_c4 + 0][a_row] = av.x;
        As[a_c4 + 1][a_row] = av.y;
        As[a_c4 + 2][a_row] = av.z;
        As[a_c4 + 3][a_row] = av.w;
        Bs[b_row][b_c4 + 0] = bv.x;
        Bs[b_row][b_c4 + 1] = bv.y;
        Bs[b_row][b_c4 + 2] = bv.z;
        Bs[b_row][b_c4 + 3] = bv.w;
        __syncthreads();
        #pragma unroll
        for (int kk = 0; kk < 16; kk++) {
            float a[4], b[4];
            #pragma unroll
            for (int i = 0; i < 4; i++) a[i] = As[kk][ty * 4 + i];
            #pragma unroll
            for (int j = 0; j < 4; j++) b[j] = Bs[kk][tx * 4 + j];
            #pragma unroll
            for (int i = 0; i < 4; i++)
                #pragma unroll
                for (int j = 0; j < 4; j++)
                    acc[i][j] = __builtin_fmaf(a[i], b[j], acc[i][j]);
        }
        __syncthreads();
    }

    #pragma unroll
    for (int i = 0; i < 4; i++) {
        float4 v = make_float4(acc[i][0], acc[i][1], acc[i][2], acc[i][3]);
        *(float4*)(C + (long)(m0 + ty * 4 + i) * N + n0 + tx * 4) = v;
    }
}

// scores -> e = exp(scores), plus column sums l[b,q] += sum_p e[b,p,q].
// One block computes a 32x32 (p,q) tile for batch b; d-loop chunked by 64.
// s[b,p,q] = sum_d vc[d]*tanh(pp[b,p,d]+pq[b,q,d]); |s| <= sum|vc| ~ 10,
// so exp without max-subtraction is safe in fp32.
__global__ __launch_bounds__(256) void score_kernel(
    const float* __restrict__ pp, const float* __restrict__ pq,
    const float* __restrict__ vc, float* __restrict__ ebuf, float* __restrict__ lbuf)
{
    const int b  = blockIdx.z;
    const int p0 = blockIdx.y * 32;
    const int q0 = blockIdx.x * 32;

    __shared__ float pps[32][65];   // +1 pad: conflict-free row reads
    __shared__ float pqs[32][65];
    __shared__ float vcs[DD];

    const int t  = threadIdx.x;
    const int tx = t & 15, ty = t >> 4;

    vcs[t] = vc[t];   // blockDim == DD == 256

    const float* ppb = pp + ((long)b * TPS + p0) * DD;
    const float* pqb = pq + ((long)b * TQS + q0) * DD;

    float acc00 = 0.f, acc01 = 0.f, acc10 = 0.f, acc11 = 0.f;

    for (int dc = 0; dc < DD; dc += 64) {
        __syncthreads();   // previous chunk fully consumed (also covers vcs store)
        // stage 32x64 chunks of pp and pq (512 float4 each; 2 per thread)
        #pragma unroll
        for (int f = t; f < 512; f += 256) {
            int r = f >> 4, c4 = (f & 15) * 4;
            float4 v = *(const float4*)(ppb + (long)r * DD + dc + c4);
            pps[r][c4 + 0] = v.x; pps[r][c4 + 1] = v.y;
            pps[r][c4 + 2] = v.z; pps[r][c4 + 3] = v.w;
            float4 w = *(const float4*)(pqb + (long)r * DD + dc + c4);
            pqs[r][c4 + 0] = w.x; pqs[r][c4 + 1] = w.y;
            pqs[r][c4 + 2] = w.z; pqs[r][c4 + 3] = w.w;
        }
        __syncthreads();
        #pragma unroll 8
        for (int d = 0; d < 64; d++) {
            float vcd = vcs[dc + d];
            float a0 = pps[ty][d],      a1 = pps[ty + 16][d];
            float b0 = pqs[tx][d],      b1 = pqs[tx + 16][d];
            acc00 = __builtin_fmaf(vcd, fast_tanh(a0 + b0), acc00);
            acc01 = __builtin_fmaf(vcd, fast_tanh(a0 + b1), acc01);
            acc10 = __builtin_fmaf(vcd, fast_tanh(a1 + b0), acc10);
            acc11 = __builtin_fmaf(vcd, fast_tanh(a1 + b1), acc11);
        }
    }

    // e = exp(s)
    const float L2E = 1.442695040888963f;
    float e00 = __builtin_amdgcn_exp2f(acc00 * L2E);
    float e01 = __builtin_amdgcn_exp2f(acc01 * L2E);
    float e10 = __builtin_amdgcn_exp2f(acc10 * L2E);
    float e11 = __builtin_amdgcn_exp2f(acc11 * L2E);

    float* eb = ebuf + (long)b * TPS * TQS;
    eb[(long)(p0 + ty) * TQS + q0 + tx]           = e00;
    eb[(long)(p0 + ty) * TQS + q0 + tx + 16]      = e01;
    eb[(long)(p0 + ty + 16) * TQS + q0 + tx]      = e10;
    eb[(long)(p0 + ty + 16) * TQS + q0 + tx + 16] = e11;

    // block-level column sums (over the 32 local p), then one atomicAdd/column
    __syncthreads();   // done with pps/pqs; reuse as scratch
    float* et = &pps[0][0];   // 32x33 <= 32x65 capacity
    et[(ty)      * 33 + tx]      = e00;
    et[(ty)      * 33 + tx + 16] = e01;
    et[(ty + 16) * 33 + tx]      = e10;
    et[(ty + 16) * 33 + tx + 16] = e11;
    __syncthreads();
    if (t < 32) {
        float s = 0.f;
        #pragma unroll
        for (int pl = 0; pl < 32; pl++) s += et[pl * 33 + t];
        atomicAdd(&lbuf[b * TQS + q0 + t], s);
    }
}

extern "C" void kernel_launch(void* const* d_in, const int* in_sizes, int n_in,
                              void* d_out, int out_size, void* d_ws, size_t ws_size,
                              hipStream_t stream) {
    const float* q  = (const float*)d_in[0];   // [4,512,256]
    const float* p  = (const float*)d_in[1];   // [4,512,256]
    const float* W0 = (const float*)d_in[2];   // [256,256]
    const float* W1 = (const float*)d_in[3];   // [256,256]
    const float* vc = (const float*)d_in[4];   // [256,1]
    float* out = (float*)d_out;                // [4,512,256]

    float* ws   = (float*)d_ws;
    float* pq   = ws;               // 4*512*256 = 524288 floats
    float* pp   = ws + 524288;      // 524288 floats
    float* ebuf = ws + 1048576;     // 4*512*512 = 1048576 floats
    float* lbuf = ws + 2097152;     // 4*512 = 2048 floats
    // total: ~8.4 MB of workspace

    hipMemsetAsync(lbuf, 0, NB * TQS * sizeof(float), stream);

    // projections: prod_q = q@W0, prod_p = p@W1  (flatten batch: 2048x256 @ 256x256)
    gemm_kernel<<<dim3(4, 32, 1), 256, 0, stream>>>(q, W0, pq, NB * TQS, DD, DD, 0, 0, 0, nullptr, 0);
    gemm_kernel<<<dim3(4, 32, 1), 256, 0, stream>>>(p, W1, pp, NB * TPS, DD, DD, 0, 0, 0, nullptr, 0);

    // scores -> exp(scores) + column sums l
    score_kernel<<<dim3(TQS / 32, TPS / 32, NB), 256, 0, stream>>>(pp, pq, vc, ebuf, lbuf);

    // out[b,p,:] = sum_q (e[b,p,q]/l[b,q]) * q[b,q,:]   (batched 512x512 @ 512x256)
    gemm_kernel<<<dim3(DD / 64, TPS / 64, NB), 256, 0, stream>>>(
        ebuf, q, out, TPS, DD, TQS,
        (long)TPS * TQS, (long)TQS * DD, (long)TPS * DD, lbuf, TQS);
}

// Round 2
// 153.315 us; speedup vs baseline: 1.3089x; 1.3089x over previous
//
#include <hip/hip_runtime.h>

#define NB 4
#define TT 512          // TQ = TP = 512
#define DD 256
#define SCALE_2L2E 2.885390081777927f        // 2/ln2 : e^{2x} = 2^{SCALE*x}
#define NEG2L2E   (-2.8853900817779268f)     // -2*log2(e)

#if defined(__has_builtin)
# if __has_builtin(__builtin_amdgcn_global_load_lds)
#  define HAS_GLL 1
# endif
#endif

__device__ __forceinline__ void stage16(const float* __restrict__ g, float* l) {
#ifdef HAS_GLL
    __builtin_amdgcn_global_load_lds((const __attribute__((address_space(1))) void*)g,
                                     (__attribute__((address_space(3))) void*)l, 16, 0, 0);
#else
    *(float4*)l = *(const float4*)g;
#endif
}

// ---------------- projections: CT[b][d][m] = SCALE * (A[b,m,:] @ W)[d] -------------
// grid (4 n-tiles, 32 m-tiles, 2 which), 256 thr, 64x64 tile, 4x4 microtile,
// reg-prefetch double buffering. Output TRANSPOSED per batch: [256 d][512 m].
__global__ __launch_bounds__(256) void proj_kernel(
    const float* __restrict__ qin, const float* __restrict__ pin,
    const float* __restrict__ W0, const float* __restrict__ W1,
    float* __restrict__ pqT, float* __restrict__ ppT)
{
    const int which = blockIdx.z;
    const float* A = which ? pin : qin;
    const float* W = which ? W1 : W0;
    float* CT      = which ? ppT : pqT;

    const int t  = threadIdx.x;
    const int tm = t & 15, tn = t >> 4;          // tm minor -> coalesced transposed store
    const int m0 = blockIdx.y * 64, n0 = blockIdx.x * 64;

    __shared__ float As[16][68];   // [k][m] transposed
    __shared__ float Bs[16][68];   // [k][n]

    const int ar = t >> 2, ac4 = (t & 3) * 4;    // A tile 64m x 16k
    const int br = t >> 4, bc4 = (t & 15) * 4;   // B tile 16k x 64n

    const float* Ap = A + (long)(m0 + ar) * DD + ac4;
    const float* Wp = W + (long)br * DD + n0 + bc4;

    float4 av = *(const float4*)Ap;
    float4 bv = *(const float4*)Wp;

    float acc[4][4] = {};

    for (int c = 0; c < 16; ++c) {
        As[ac4 + 0][ar] = av.x; As[ac4 + 1][ar] = av.y;
        As[ac4 + 2][ar] = av.z; As[ac4 + 3][ar] = av.w;
        *(float4*)&Bs[br][bc4] = bv;
        __syncthreads();
        if (c < 15) {
            av = *(const float4*)(Ap + (c + 1) * 16);
            bv = *(const float4*)(Wp + (long)(c + 1) * 16 * DD);
        }
        #pragma unroll
        for (int kk = 0; kk < 16; ++kk) {
            float4 a = *(const float4*)&As[kk][4 * tm];
            float4 b = *(const float4*)&Bs[kk][4 * tn];
            float aa[4] = {a.x, a.y, a.z, a.w};
            float bb[4] = {b.x, b.y, b.z, b.w};
            #pragma unroll
            for (int i = 0; i < 4; ++i)
                #pragma unroll
                for (int j = 0; j < 4; ++j)
                    acc[i][j] = __builtin_fmaf(aa[i], bb[j], acc[i][j]);
        }
        __syncthreads();
    }

    const int bz = m0 >> 9, mloc = m0 & 511;
    float* C = CT + (long)bz * (DD * TT) + mloc + 4 * tm;
    #pragma unroll
    for (int j = 0; j < 4; ++j) {
        float4 v;
        v.x = acc[0][j] * SCALE_2L2E; v.y = acc[1][j] * SCALE_2L2E;
        v.z = acc[2][j] * SCALE_2L2E; v.w = acc[3][j] * SCALE_2L2E;
        *(float4*)(C + (long)(n0 + 4 * tn + j) * TT) = v;
    }
}

// ---------------- score kernel --------------------------------------------
// e[b,p,q] = exp(sum_d vc_d * tanh(pp+pq)); lpart[b][pb][q] = partial col sums.
// 64x64 (p,q) tile, 512 thr, microtile 2p x 4q, async LDS double buffer,
// paired-d: vc0/(1+E0)+vc1/(1+E1) = (vs+vc0*E1+vc1*E0)*rcp(1+E0+E1+E0*E1).
__global__ __launch_bounds__(512) void score_kernel(
    const float* __restrict__ ppT, const float* __restrict__ pqT,
    const float* __restrict__ vc, float* __restrict__ ebuf, float* __restrict__ lpart)
{
    const int b  = blockIdx.z;
    const int q0 = blockIdx.x * 64, p0 = blockIdx.y * 64;
    const int t  = threadIdx.x;
    const int qx = t & 15, py = t >> 4;          // qx: q-quad, py: p-pair (0..31)

    __shared__ float Pbuf[2][64 * 64];           // [d][p]
    __shared__ float Qbuf[2][64 * 64];           // [d][q]
    __shared__ float vcn[DD];
    __shared__ float wpart[4];

    const float* Pg = ppT + (long)b * DD * TT + p0;
    const float* Qg = pqT + (long)b * DD * TT + q0;

    // stage chunk 0 (async, lane-contiguous: LDS offset = f*16B)
    #pragma unroll
    for (int pa = 0; pa < 2; ++pa) {
        int f = t + pa * 512;
        int dr = f >> 4, c4 = (f & 15) * 4;
        stage16(Pg + (long)dr * TT + c4, &Pbuf[0][f * 4]);
        stage16(Qg + (long)dr * TT + c4, &Qbuf[0][f * 4]);
    }
    // vcn = -2*log2e*vc ; per-wave reduction for Svc
    if (t < DD) {
        float v = vc[t] * NEG2L2E;
        vcn[t] = v;
        float s = v;
        #pragma unroll
        for (int m = 1; m < 64; m <<= 1) s += __shfl_xor(s, m, 64);
        if ((t & 63) == 0) wpart[t >> 6] = s;
    }
    __syncthreads();   // drains chunk0 loads + vcn writes

    float acc[2][4] = {};

    for (int c = 0; c < 4; ++c) {
        if (c < 3) {
            #pragma unroll
            for (int pa = 0; pa < 2; ++pa) {
                int f = t + pa * 512;
                int dr = f >> 4, c4 = (f & 15) * 4;
                stage16(Pg + (long)((c + 1) * 64 + dr) * TT + c4, &Pbuf[(c + 1) & 1][f * 4]);
                stage16(Qg + (long)((c + 1) * 64 + dr) * TT + c4, &Qbuf[(c + 1) & 1][f * 4]);
            }
        }
        const float* P = Pbuf[c & 1];
        const float* Q = Qbuf[c & 1];
        const float* vcc = &vcn[c * 64];
        #pragma unroll 8
        for (int dp = 0; dp < 32; ++dp) {
            float2 vp = *(const float2*)&vcc[2 * dp];
            float vs = vp.x + vp.y;
            float2 a0 = *(const float2*)&P[(2 * dp) * 64 + 2 * py];
            float2 a1 = *(const float2*)&P[(2 * dp + 1) * 64 + 2 * py];
            float4 b0 = *(const float4*)&Q[(2 * dp) * 64 + 4 * qx];
            float4 b1 = *(const float4*)&Q[(2 * dp + 1) * 64 + 4 * qx];
            float a0a[2] = {a0.x, a0.y}, a1a[2] = {a1.x, a1.y};
            float b0a[4] = {b0.x, b0.y, b0.z, b0.w};
            float b1a[4] = {b1.x, b1.y, b1.z, b1.w};
            #pragma unroll
            for (int i = 0; i < 2; ++i)
                #pragma unroll
                for (int j = 0; j < 4; ++j) {
                    float E0 = __builtin_amdgcn_exp2f(a0a[i] + b0a[j]);
                    float E1 = __builtin_amdgcn_exp2f(a1a[i] + b1a[j]);
                    float u    = 1.0f + (E0 + E1);
                    float prod = __builtin_fmaf(E0, E1, u);
                    float rp   = __builtin_amdgcn_rcpf(prod);
                    float num  = __builtin_fmaf(vp.x, E1, vs);
                    num        = __builtin_fmaf(vp.y, E0, num);
                    acc[i][j]  = __builtin_fmaf(num, rp, acc[i][j]);
                }
        }
        __syncthreads();
    }

    const float SvcL = -0.5f * (wpart[0] + wpart[1] + wpart[2] + wpart[3]);
    float* eb = ebuf + ((long)b * TT + p0) * TT + q0;
    float colp[4] = {0.f, 0.f, 0.f, 0.f};
    #pragma unroll
    for (int i = 0; i < 2; ++i) {
        float4 ev;
        ev.x = __builtin_amdgcn_exp2f(acc[i][0] + SvcL);
        ev.y = __builtin_amdgcn_exp2f(acc[i][1] + SvcL);
        ev.z = __builtin_amdgcn_exp2f(acc[i][2] + SvcL);
        ev.w = __builtin_amdgcn_exp2f(acc[i][3] + SvcL);
        *(float4*)(eb + (long)(2 * py + i) * TT + 4 * qx) = ev;
        colp[0] += ev.x; colp[1] += ev.y; colp[2] += ev.z; colp[3] += ev.w;
    }
    float* scr = (float*)&Pbuf[0][0];   // all compute done (loop-end barrier)
    *(float4*)&scr[py * 64 + 4 * qx] = make_float4(colp[0], colp[1], colp[2], colp[3]);
    __syncthreads();
    if (t < 64) {
        float s = 0.f;
        #pragma unroll
        for (int r = 0; r < 32; ++r) s += scr[r * 64 + t];
        lpart[((long)b * 8 + blockIdx.y) * TT + q0 + t] = s;
    }
}

// ---------------- final GEMM: out[b,p,:] = sum_q (e[p,q]/l[q]) * qin[b,q,:] ------
// 32x64 tile, 256 thr, microtile 2x4, K-chunk 32, reg-prefetch, 256 blocks.
__global__ __launch_bounds__(256) void out_gemm(
    const float* __restrict__ ebuf, const float* __restrict__ qin,
    const float* __restrict__ lpart, float* __restrict__ out)
{
    const int b  = blockIdx.z;
    const int t  = threadIdx.x;
    const int tx = t & 15, ty = t >> 4;
    const int m0 = blockIdx.y * 32, n0 = blockIdx.x * 64;

    __shared__ float As[32][34];   // [k][m] transposed
    __shared__ float Bs[32][68];   // [k][n], rows pre-scaled by 1/l[k]

    const float* A  = ebuf + ((long)b * TT + m0) * TT;    // 32 x 512
    const float* B  = qin + (long)b * TT * DD;            // 512 x 256
    const float* lp = lpart + (long)b * 8 * TT;

    const int arr = t >> 3, ac4 = (t & 7) * 4;            // A: 32m x 32k
    const int brr = t >> 4, bc4 = (t & 15) * 4;           // B pass rows brr, brr+16

    float4 av = *(const float4*)(A + (long)arr * TT + ac4);
    float4 bv0 = *(const float4*)(B + (long)brr * DD + n0 + bc4);
    float4 bv1 = *(const float4*)(B + (long)(brr + 16) * DD + n0 + bc4);
    float sc0, sc1;
    {
        float s0 = 0.f, s1 = 0.f;
        #pragma unroll
        for (int pb = 0; pb < 8; ++pb) { s0 += lp[pb * TT + brr]; s1 += lp[pb * TT + 16 + brr]; }
        sc0 = __builtin_amdgcn_rcpf(s0); sc1 = __builtin_amdgcn_rcpf(s1);
    }

    float acc[2][4] = {};

    for (int c = 0; c < 16; ++c) {
        As[ac4 + 0][arr] = av.x; As[ac4 + 1][arr] = av.y;
        As[ac4 + 2][arr] = av.z; As[ac4 + 3][arr] = av.w;
        float4 w0; w0.x = bv0.x * sc0; w0.y = bv0.y * sc0; w0.z = bv0.z * sc0; w0.w = bv0.w * sc0;
        float4 w1; w1.x = bv1.x * sc1; w1.y = bv1.y * sc1; w1.z = bv1.z * sc1; w1.w = bv1.w * sc1;
        *(float4*)&Bs[brr][bc4] = w0;
        *(float4*)&Bs[brr + 16][bc4] = w1;
        __syncthreads();
        if (c < 15) {
            int k1 = (c + 1) * 32;
            av  = *(const float4*)(A + (long)arr * TT + k1 + ac4);
            bv0 = *(const float4*)(B + (long)(k1 + brr) * DD + n0 + bc4);
            bv1 = *(const float4*)(B + (long)(k1 + 16 + brr) * DD + n0 + bc4);
            float s0 = 0.f, s1 = 0.f;
            #pragma unroll
            for (int pb = 0; pb < 8; ++pb) { s0 += lp[pb * TT + k1 + brr]; s1 += lp[pb * TT + k1 + 16 + brr]; }
            sc0 = __builtin_amdgcn_rcpf(s0); sc1 = __builtin_amdgcn_rcpf(s1);
        }
        #pragma unroll
        for (int kk = 0; kk < 32; ++kk) {
            float2 a = *(const float2*)&As[kk][2 * ty];
            float4 bb = *(const float4*)&Bs[kk][4 * tx];
            float bba[4] = {bb.x, bb.y, bb.z, bb.w};
            #pragma unroll
            for (int j = 0; j < 4; ++j) {
                acc[0][j] = __builtin_fmaf(a.x, bba[j], acc[0][j]);
                acc[1][j] = __builtin_fmaf(a.y, bba[j], acc[1][j]);
            }
        }
        __syncthreads();
    }

    float* C = out + ((long)b * TT + m0) * DD + n0;
    #pragma unroll
    for (int i = 0; i < 2; ++i) {
        float4 v = make_float4(acc[i][0], acc[i][1], acc[i][2], acc[i][3]);
        *(float4*)(C + (long)(2 * ty + i) * DD + 4 * tx) = v;
    }
}

extern "C" void kernel_launch(void* const* d_in, const int* in_sizes, int n_in,
                              void* d_out, int out_size, void* d_ws, size_t ws_size,
                              hipStream_t stream) {
    const float* q  = (const float*)d_in[0];   // [4,512,256]
    const float* p  = (const float*)d_in[1];   // [4,512,256]
    const float* W0 = (const float*)d_in[2];   // [256,256]
    const float* W1 = (const float*)d_in[3];   // [256,256]
    const float* vc = (const float*)d_in[4];   // [256]
    float* out = (float*)d_out;                // [4,512,256]

    float* ws    = (float*)d_ws;
    float* pqT   = ws;                 // 4 * 256 * 512 = 524288  ([b][d][q], pre-scaled)
    float* ppT   = ws + 524288;        // 524288                  ([b][d][p], pre-scaled)
    float* ebuf  = ws + 1048576;       // 4*512*512 = 1048576     ([b][p][q])
    float* lpart = ws + 2097152;       // 4*8*512 = 16384         ([b][pblock][q])

    proj_kernel<<<dim3(4, 32, 2), 256, 0, stream>>>(q, p, W0, W1, pqT, ppT);
    score_kernel<<<dim3(8, 8, NB), 512, 0, stream>>>(ppT, pqT, vc, ebuf, lpart);
    out_gemm<<<dim3(4, 16, NB), 256, 0, stream>>>(ebuf, q, lpart, out);
}

// Round 3
// 131.035 us; speedup vs baseline: 1.5315x; 1.1700x over previous
//
#include <hip/hip_runtime.h>

#define NB 4
#define TT 512          // TQ = TP
#define DD 256
#define K2L2E    2.885390081777927f     // 2*log2(e): e^{2x} = 2^{K*x}
#define NEG2L2E (-2.885390081777927f)

#if defined(__has_builtin)
# if __has_builtin(__builtin_amdgcn_global_load_lds)
#  define HAS_GLL 1
# endif
#endif

__device__ __forceinline__ void stage16(const float* __restrict__ g, float* l) {
#ifdef HAS_GLL
    __builtin_amdgcn_global_load_lds((const __attribute__((address_space(1))) void*)g,
                                     (__attribute__((address_space(3))) void*)l, 16, 0, 0);
#else
    *(float4*)l = *(const float4*)g;
#endif
}

// ============ P1: projections + exp epilogue ============
// expQ[b][d][q] = 2^(K2L2E * (q@W0)[q,d]) = e^{2*pq};  expP likewise from p@W1.
// 512 blocks: blk>>8 selects projection; 32m x 64n tile, 256 thr, 2x4 microtile.
__global__ __launch_bounds__(256) void proj_exp_kernel(
    const float* __restrict__ qin, const float* __restrict__ pin,
    const float* __restrict__ W0, const float* __restrict__ W1,
    float* __restrict__ expQ, float* __restrict__ expP)
{
    const int blk = blockIdx.x;
    const int wh = blk >> 8, tid = blk & 255;
    const int m0 = (tid >> 2) * 32, n0 = (tid & 3) * 64;   // m over 2048 rows, n over 256 d
    const float* A = wh ? pin : qin;
    const float* W = wh ? W1 : W0;
    float* OUT     = wh ? expP : expQ;

    __shared__ __align__(16) float As[32 * 34];   // [k][m], pad 34 (8B-aligned float2 rows)
    __shared__ __align__(16) float Bs[32 * 64];   // [k][n]

    const int t  = threadIdx.x;
    const int ar = t >> 3, ac4 = (t & 7) * 4;      // A stage: row ar(m), cols ac4(k)
    const int br = t >> 4, bc4 = (t & 15) * 4;     // B stage: rows br,br+16(k), cols bc4(n)
    const int tn = t >> 4, tm = t & 15;            // microtile: m=2tm+i (store-coalesced), n=4tn+j

    const float* Ap = A + (long)(m0 + ar) * DD + ac4;

    float4 av  = *(const float4*)Ap;
    float4 bv0 = *(const float4*)(W + (long)br * DD + n0 + bc4);
    float4 bv1 = *(const float4*)(W + (long)(br + 16) * DD + n0 + bc4);

    float acc[2][4] = {};

    for (int c = 0; c < 8; ++c) {
        As[(ac4 + 0) * 34 + ar] = av.x;
        As[(ac4 + 1) * 34 + ar] = av.y;
        As[(ac4 + 2) * 34 + ar] = av.z;
        As[(ac4 + 3) * 34 + ar] = av.w;
        *(float4*)&Bs[br * 64 + bc4]        = bv0;
        *(float4*)&Bs[(br + 16) * 64 + bc4] = bv1;
        __syncthreads();
        if (c < 7) {
            int k1 = (c + 1) * 32;
            av  = *(const float4*)(Ap + k1);
            bv0 = *(const float4*)(W + (long)(k1 + br) * DD + n0 + bc4);
            bv1 = *(const float4*)(W + (long)(k1 + 16 + br) * DD + n0 + bc4);
        }
        #pragma unroll
        for (int kk = 0; kk < 32; ++kk) {
            float2 a = *(const float2*)&As[kk * 34 + 2 * tm];
            float4 b = *(const float4*)&Bs[kk * 64 + 4 * tn];
            float aa[2] = {a.x, a.y};
            float bb[4] = {b.x, b.y, b.z, b.w};
            #pragma unroll
            for (int i = 0; i < 2; ++i)
                #pragma unroll
                for (int j = 0; j < 4; ++j)
                    acc[i][j] = __builtin_fmaf(aa[i], bb[j], acc[i][j]);
        }
        __syncthreads();
    }

    const int  bi = m0 >> 9;
    const int  ml = (m0 & 511) + 2 * tm;
    #pragma unroll
    for (int j = 0; j < 4; ++j) {
        int d = n0 + 4 * tn + j;
        float2 st;
        st.x = __builtin_amdgcn_exp2f(acc[0][j] * K2L2E);
        st.y = __builtin_amdgcn_exp2f(acc[1][j] * K2L2E);
        *(float2*)(OUT + ((long)bi * DD + d) * TT + ml) = st;
    }
}

// ============ P2: scores ============
// e[b,p,q] = exp(sum_d v_d*tanh(.)) modulo a constant factor (Svc dropped — cancels
// in softmax). Inner loop: E = EA*EB; pair-rcp over 2 d's. No exp in the loop.
// 32p x 64q tile, 256 thr, 2p x 4q microtile, d-chunk 64, async dbuf staging.
__global__ __launch_bounds__(256) void score_kernel(
    const float* __restrict__ expP, const float* __restrict__ expQ,
    const float* __restrict__ vc, float* __restrict__ ebuf, float* __restrict__ lpart)
{
    const int b = blockIdx.z, pt = blockIdx.y, qt = blockIdx.x;
    const int p0 = pt * 32, q0 = qt * 64;
    const int t  = threadIdx.x;
    const int qx = t & 15, py = t >> 4;

    __shared__ __align__(16) float PA[2][64 * 32];   // [d][p]
    __shared__ __align__(16) float QB[2][64 * 64];   // [d][q]
    __shared__ float vcs[DD];

    const float* gP = expP + (long)b * DD * TT + p0;
    const float* gQ = expQ + (long)b * DD * TT + q0;

    #pragma unroll
    for (int s = 0; s < 2; ++s) {
        int f = t + 256 * s, d = f >> 3, off = (f & 7) * 4;
        stage16(gP + (long)d * TT + off, &PA[0][f * 4]);
    }
    #pragma unroll
    for (int s = 0; s < 4; ++s) {
        int f = t + 256 * s, d = f >> 4, off = (f & 15) * 4;
        stage16(gQ + (long)d * TT + off, &QB[0][f * 4]);
    }
    vcs[t] = vc[t];
    __syncthreads();

    float acc[2][4] = {};

    for (int c = 0; c < 4; ++c) {
        if (c < 3) {
            int dc = (c + 1) * 64, nb = (c + 1) & 1;
            #pragma unroll
            for (int s = 0; s < 2; ++s) {
                int f = t + 256 * s, d = f >> 3, off = (f & 7) * 4;
                stage16(gP + (long)(dc + d) * TT + off, &PA[nb][f * 4]);
            }
            #pragma unroll
            for (int s = 0; s < 4; ++s) {
                int f = t + 256 * s, d = f >> 4, off = (f & 15) * 4;
                stage16(gQ + (long)(dc + d) * TT + off, &QB[nb][f * 4]);
            }
        }
        const float* PAc = PA[c & 1];
        const float* QBc = QB[c & 1];
        const float* vcb = &vcs[c * 64];
        #pragma unroll 8
        for (int dp = 0; dp < 32; ++dp) {
            float2 vp = *(const float2*)&vcb[2 * dp];
            float vs = vp.x + vp.y;
            float2 A0 = *(const float2*)&PAc[(2 * dp) * 32 + 2 * py];
            float2 A1 = *(const float2*)&PAc[(2 * dp + 1) * 32 + 2 * py];
            float4 B0 = *(const float4*)&QBc[(2 * dp) * 64 + 4 * qx];
            float4 B1 = *(const float4*)&QBc[(2 * dp + 1) * 64 + 4 * qx];
            float a0[2] = {A0.x, A0.y}, a1[2] = {A1.x, A1.y};
            float b0[4] = {B0.x, B0.y, B0.z, B0.w};
            float b1[4] = {B1.x, B1.y, B1.z, B1.w};
            #pragma unroll
            for (int i = 0; i < 2; ++i)
                #pragma unroll
                for (int j = 0; j < 4; ++j) {
                    float E0  = a0[i] * b0[j];
                    float E1  = a1[i] * b1[j];
                    float u   = 1.0f + (E0 + E1);
                    float den = __builtin_fmaf(E0, E1, u);       // (1+E0)(1+E1)
                    float num = __builtin_fmaf(vp.y, E0, __builtin_fmaf(vp.x, E1, vs));
                    acc[i][j] = __builtin_fmaf(num, __builtin_amdgcn_rcpf(den), acc[i][j]);
                }
        }
        __syncthreads();
    }

    // e = exp2(-2*log2e * acc); write + per-block column sums
    float* eb = ebuf + ((long)b * TT + p0) * TT + q0;
    float colp[4] = {0.f, 0.f, 0.f, 0.f};
    #pragma unroll
    for (int i = 0; i < 2; ++i) {
        float4 ev;
        ev.x = __builtin_amdgcn_exp2f(acc[i][0] * NEG2L2E);
        ev.y = __builtin_amdgcn_exp2f(acc[i][1] * NEG2L2E);
        ev.z = __builtin_amdgcn_exp2f(acc[i][2] * NEG2L2E);
        ev.w = __builtin_amdgcn_exp2f(acc[i][3] * NEG2L2E);
        *(float4*)(eb + (long)(2 * py + i) * TT + 4 * qx) = ev;
        colp[0] += ev.x; colp[1] += ev.y; colp[2] += ev.z; colp[3] += ev.w;
    }
    float* scr = (float*)&PA[0][0];   // safe: loop ended with barrier
    *(float4*)&scr[py * 64 + 4 * qx] = make_float4(colp[0], colp[1], colp[2], colp[3]);
    __syncthreads();
    if (t < 64) {
        float s = 0.f;
        #pragma unroll
        for (int r = 0; r < 16; ++r) s += scr[r * 64 + t];
        lpart[((long)b * 16 + pt) * TT + q0 + t] = s;
    }
}

// ============ P4: out[b,p,:] = sum_q (e[p,q]/l[q]) * qin[b,q,:] ============
// 32m x 32n tile, 256 thr, 2x2 microtile, K-chunk 64, linv computed once per block.
__global__ __launch_bounds__(256) void out_kernel(
    const float* __restrict__ ebuf, const float* __restrict__ qin,
    const float* __restrict__ lpart, float* __restrict__ out)
{
    const int b = blockIdx.z, mt = blockIdx.y, nt = blockIdx.x;
    const int m0 = mt * 32, n0 = nt * 32;
    const int t  = threadIdx.x;
    const int tm = t >> 4, tn = t & 15;            // m=2tm+i, n=2tn+j (n-coalesced store)

    __shared__ __align__(16) float As[64 * 34];    // [k][m]
    __shared__ __align__(16) float Bs[64 * 36];    // [k][n], pre-scaled by linv[k]
    __shared__ float linv[TT];

    #pragma unroll
    for (int s = 0; s < 2; ++s) {
        int qq = t + 256 * s;
        float sum = 0.f;
        #pragma unroll
        for (int pb = 0; pb < 16; ++pb) sum += lpart[((long)b * 16 + pb) * TT + qq];
        linv[qq] = __builtin_amdgcn_rcpf(sum);
    }
    __syncthreads();

    const float* Ab = ebuf + ((long)b * TT + m0) * TT;   // 32 x 512
    const float* Bb = qin + (long)b * TT * DD + n0;      // 512 x 32

    const int ara = t >> 4, aca = (t & 15) * 4;          // A: rows ara, ara+16? no: +16 via s
    const int brb = t >> 3, bcb = (t & 7) * 4;           // B: rows brb, brb+32

    float4 av0 = *(const float4*)(Ab + (long)ara * TT + aca);
    float4 av1 = *(const float4*)(Ab + (long)(ara + 16) * TT + aca);
    float4 bv0 = *(const float4*)(Bb + (long)brb * DD + bcb);
    float4 bv1 = *(const float4*)(Bb + (long)(brb + 32) * DD + bcb);

    float acc[2][2] = {};

    for (int c = 0; c < 8; ++c) {
        const int k0 = c * 64;
        // A transpose-store: local k = aca+u, m = ara / ara+16
        As[(aca + 0) * 34 + ara] = av0.x;
        As[(aca + 1) * 34 + ara] = av0.y;
        As[(aca + 2) * 34 + ara] = av0.z;
        As[(aca + 3) * 34 + ara] = av0.w;
        As[(aca + 0) * 34 + ara + 16] = av1.x;
        As[(aca + 1) * 34 + ara + 16] = av1.y;
        As[(aca + 2) * 34 + ara + 16] = av1.z;
        As[(aca + 3) * 34 + ara + 16] = av1.w;
        {
            float s0 = linv[k0 + brb], s1 = linv[k0 + brb + 32];
            float4 w0, w1;
            w0.x = bv0.x * s0; w0.y = bv0.y * s0; w0.z = bv0.z * s0; w0.w = bv0.w * s0;
            w1.x = bv1.x * s1; w1.y = bv1.y * s1; w1.z = bv1.z * s1; w1.w = bv1.w * s1;
            *(float4*)&Bs[brb * 36 + bcb]        = w0;
            *(float4*)&Bs[(brb + 32) * 36 + bcb] = w1;
        }
        __syncthreads();
        if (c < 7) {
            int k1 = (c + 1) * 64;
            av0 = *(const float4*)(Ab + (long)ara * TT + k1 + aca);
            av1 = *(const float4*)(Ab + (long)(ara + 16) * TT + k1 + aca);
            bv0 = *(const float4*)(Bb + (long)(k1 + brb) * DD + bcb);
            bv1 = *(const float4*)(Bb + (long)(k1 + brb + 32) * DD + bcb);
        }
        #pragma unroll
        for (int kk = 0; kk < 64; ++kk) {
            float2 a = *(const float2*)&As[kk * 34 + 2 * tm];
            float2 bb = *(const float2*)&Bs[kk * 36 + 2 * tn];
            acc[0][0] = __builtin_fmaf(a.x, bb.x, acc[0][0]);
            acc[0][1] = __builtin_fmaf(a.x, bb.y, acc[0][1]);
            acc[1][0] = __builtin_fmaf(a.y, bb.x, acc[1][0]);
            acc[1][1] = __builtin_fmaf(a.y, bb.y, acc[1][1]);
        }
        __syncthreads();
    }

    #pragma unroll
    for (int i = 0; i < 2; ++i) {
        float2 v = make_float2(acc[i][0], acc[i][1]);
        *(float2*)(out + ((long)b * TT + m0 + 2 * tm + i) * DD + n0 + 2 * tn) = v;
    }
}

extern "C" void kernel_launch(void* const* d_in, const int* in_sizes, int n_in,
                              void* d_out, int out_size, void* d_ws, size_t ws_size,
                              hipStream_t stream) {
    const float* q  = (const float*)d_in[0];
    const float* p  = (const float*)d_in[1];
    const float* W0 = (const float*)d_in[2];
    const float* W1 = (const float*)d_in[3];
    const float* vc = (const float*)d_in[4];
    float* out = (float*)d_out;

    float* ws    = (float*)d_ws;
    float* expQ  = ws;                // [4][256][512] = 524288
    float* expP  = ws + 524288;       // 524288
    float* ebuf  = ws + 1048576;      // [4][512][512] = 1048576
    float* lpart = ws + 2097152;      // [4][16][512] = 32768

    proj_exp_kernel<<<dim3(512), 256, 0, stream>>>(q, p, W0, W1, expQ, expP);
    score_kernel<<<dim3(8, 16, NB), 256, 0, stream>>>(expP, expQ, vc, ebuf, lpart);
    out_kernel<<<dim3(8, 16, NB), 256, 0, stream>>>(ebuf, q, lpart, out);
}

// Round 4
// 128.518 us; speedup vs baseline: 1.5615x; 1.0196x over previous
//
#include <hip/hip_runtime.h>

#define NB 4
#define TT 512          // TQ = TP
#define DD 256
#define K2L2E    2.885390081777927f     // 2*log2(e): e^{2x} = 2^{K*x}
#define NEG2L2E (-2.885390081777927f)

#if defined(__has_builtin)
# if __has_builtin(__builtin_amdgcn_global_load_lds)
#  define HAS_GLL 1
# endif
#endif

__device__ __forceinline__ void stage16(const float* __restrict__ g, float* l) {
#ifdef HAS_GLL
    __builtin_amdgcn_global_load_lds((const __attribute__((address_space(1))) void*)g,
                                     (__attribute__((address_space(3))) void*)l, 16, 0, 0);
#else
    *(float4*)l = *(const float4*)g;
#endif
}

// ============ P1: projections + exp epilogue ============
// expQ[b][d][q] = 2^(K2L2E * (q@W0)[q,d]) = e^{2*pq};  expP likewise from p@W1.
// 512 blocks: blk>>8 selects projection; 32m x 64n tile, 256 thr, 2x4 microtile.
__global__ __launch_bounds__(256) void proj_exp_kernel(
    const float* __restrict__ qin, const float* __restrict__ pin,
    const float* __restrict__ W0, const float* __restrict__ W1,
    float* __restrict__ expQ, float* __restrict__ expP)
{
    const int blk = blockIdx.x;
    const int wh = blk >> 8, tid = blk & 255;
    const int m0 = (tid >> 2) * 32, n0 = (tid & 3) * 64;   // m over 2048 rows, n over 256 d
    const float* A = wh ? pin : qin;
    const float* W = wh ? W1 : W0;
    float* OUT     = wh ? expP : expQ;

    __shared__ __align__(16) float As[32 * 34];   // [k][m]
    __shared__ __align__(16) float Bs[32 * 64];   // [k][n]

    const int t  = threadIdx.x;
    const int ar = t >> 3, ac4 = (t & 7) * 4;
    const int br = t >> 4, bc4 = (t & 15) * 4;
    const int tn = t >> 4, tm = t & 15;

    const float* Ap = A + (long)(m0 + ar) * DD + ac4;

    float4 av  = *(const float4*)Ap;
    float4 bv0 = *(const float4*)(W + (long)br * DD + n0 + bc4);
    float4 bv1 = *(const float4*)(W + (long)(br + 16) * DD + n0 + bc4);

    float acc[2][4] = {};

    for (int c = 0; c < 8; ++c) {
        As[(ac4 + 0) * 34 + ar] = av.x;
        As[(ac4 + 1) * 34 + ar] = av.y;
        As[(ac4 + 2) * 34 + ar] = av.z;
        As[(ac4 + 3) * 34 + ar] = av.w;
        *(float4*)&Bs[br * 64 + bc4]        = bv0;
        *(float4*)&Bs[(br + 16) * 64 + bc4] = bv1;
        __syncthreads();
        if (c < 7) {
            int k1 = (c + 1) * 32;
            av  = *(const float4*)(Ap + k1);
            bv0 = *(const float4*)(W + (long)(k1 + br) * DD + n0 + bc4);
            bv1 = *(const float4*)(W + (long)(k1 + 16 + br) * DD + n0 + bc4);
        }
        #pragma unroll
        for (int kk = 0; kk < 32; ++kk) {
            float2 a = *(const float2*)&As[kk * 34 + 2 * tm];
            float4 b = *(const float4*)&Bs[kk * 64 + 4 * tn];
            float aa[2] = {a.x, a.y};
            float bb[4] = {b.x, b.y, b.z, b.w};
            #pragma unroll
            for (int i = 0; i < 2; ++i)
                #pragma unroll
                for (int j = 0; j < 4; ++j)
                    acc[i][j] = __builtin_fmaf(aa[i], bb[j], acc[i][j]);
        }
        __syncthreads();
    }

    const int  bi = m0 >> 9;
    const int  ml = (m0 & 511) + 2 * tm;
    #pragma unroll
    for (int j = 0; j < 4; ++j) {
        int d = n0 + 4 * tn + j;
        float2 st;
        st.x = __builtin_amdgcn_exp2f(acc[0][j] * K2L2E);
        st.y = __builtin_amdgcn_exp2f(acc[1][j] * K2L2E);
        *(float2*)(OUT + ((long)bi * DD + d) * TT + ml) = st;
    }
}

// ============ P2: scores ============
// 32p x 64q tile, 512 thr (8 waves -> 4 waves/SIMD at 2 blocks/CU), 2p x 2q
// microtile, d-chunk 64, async dbuf staging. Inner loop: E = EA*EB, pair-rcp.
__global__ __launch_bounds__(512, 4) void score_kernel(
    const float* __restrict__ expP, const float* __restrict__ expQ,
    const float* __restrict__ vc, float* __restrict__ ebuf, float* __restrict__ lpart)
{
    const int b = blockIdx.z, pt = blockIdx.y, qt = blockIdx.x;
    const int p0 = pt * 32, q0 = qt * 64;
    const int t  = threadIdx.x;
    const int qx = t & 31, py = t >> 5;          // q = q0+2qx+j, p = p0+2py+i

    __shared__ __align__(16) float PA[2][64 * 32];   // [d][p] 8KB each
    __shared__ __align__(16) float QB[2][64 * 64];   // [d][q] 16KB each
    __shared__ float vcs[DD];

    const float* gP = expP + (long)b * DD * TT + p0;
    const float* gQ = expQ + (long)b * DD * TT + q0;

    // stage chunk 0: P = 512 float4 (1/thread), Q = 1024 float4 (2/thread)
    {
        int d = t >> 3, off = (t & 7) * 4;
        stage16(gP + (long)d * TT + off, &PA[0][t * 4]);
    }
    #pragma unroll
    for (int s = 0; s < 2; ++s) {
        int f = t + 512 * s, d = f >> 4, off = (f & 15) * 4;
        stage16(gQ + (long)d * TT + off, &QB[0][f * 4]);
    }
    if (t < DD) vcs[t] = vc[t];
    __syncthreads();

    float acc[2][2] = {};

    for (int c = 0; c < 4; ++c) {
        if (c < 3) {
            int dc = (c + 1) * 64, nb = (c + 1) & 1;
            {
                int d = t >> 3, off = (t & 7) * 4;
                stage16(gP + (long)(dc + d) * TT + off, &PA[nb][t * 4]);
            }
            #pragma unroll
            for (int s = 0; s < 2; ++s) {
                int f = t + 512 * s, d = f >> 4, off = (f & 15) * 4;
                stage16(gQ + (long)(dc + d) * TT + off, &QB[nb][f * 4]);
            }
        }
        const float* PAc = PA[c & 1];
        const float* QBc = QB[c & 1];
        const float* vcb = &vcs[c * 64];
        #pragma unroll 8
        for (int dp = 0; dp < 32; ++dp) {
            float2 vp = *(const float2*)&vcb[2 * dp];
            float vs = vp.x + vp.y;
            float2 A0 = *(const float2*)&PAc[(2 * dp) * 32 + 2 * py];
            float2 A1 = *(const float2*)&PAc[(2 * dp + 1) * 32 + 2 * py];
            float2 B0 = *(const float2*)&QBc[(2 * dp) * 64 + 2 * qx];
            float2 B1 = *(const float2*)&QBc[(2 * dp + 1) * 64 + 2 * qx];
            float a0[2] = {A0.x, A0.y}, a1[2] = {A1.x, A1.y};
            float b0[2] = {B0.x, B0.y}, b1[2] = {B1.x, B1.y};
            #pragma unroll
            for (int i = 0; i < 2; ++i)
                #pragma unroll
                for (int j = 0; j < 2; ++j) {
                    float E0  = a0[i] * b0[j];
                    float E1  = a1[i] * b1[j];
                    float u   = 1.0f + (E0 + E1);
                    float den = __builtin_fmaf(E0, E1, u);       // (1+E0)(1+E1)
                    float num = __builtin_fmaf(vp.y, E0, __builtin_fmaf(vp.x, E1, vs));
                    acc[i][j] = __builtin_fmaf(num, __builtin_amdgcn_rcpf(den), acc[i][j]);
                }
        }
        __syncthreads();
    }

    // e = exp2(NEG2L2E * acc); write + per-block column partial sums
    float* eb = ebuf + ((long)b * TT + p0) * TT + q0;
    float colp[2] = {0.f, 0.f};
    #pragma unroll
    for (int i = 0; i < 2; ++i) {
        float2 ev;
        ev.x = __builtin_amdgcn_exp2f(acc[i][0] * NEG2L2E);
        ev.y = __builtin_amdgcn_exp2f(acc[i][1] * NEG2L2E);
        *(float2*)(eb + (long)(2 * py + i) * TT + 2 * qx) = ev;
        colp[0] += ev.x; colp[1] += ev.y;
    }
    float* scr = (float*)&PA[0][0];   // safe: loop ended with barrier; 16x64 <= 8KB
    *(float2*)&scr[py * 64 + 2 * qx] = make_float2(colp[0], colp[1]);
    __syncthreads();
    if (t < 64) {
        float s = 0.f;
        #pragma unroll
        for (int r = 0; r < 16; ++r) s += scr[r * 64 + t];
        lpart[((long)b * 16 + pt) * TT + q0 + t] = s;
    }
}

// ============ P3: out[b,p,:] = sum_q (e[p,q]/l[q]) * qin[b,q,:] ============
// 32m x 32n tile, 256 thr, 2x2 microtile, K-chunk 64, linv computed once per block.
__global__ __launch_bounds__(256) void out_kernel(
    const float* __restrict__ ebuf, const float* __restrict__ qin,
    const float* __restrict__ lpart, float* __restrict__ out)
{
    const int b = blockIdx.z, mt = blockIdx.y, nt = blockIdx.x;
    const int m0 = mt * 32, n0 = nt * 32;
    const int t  = threadIdx.x;
    const int tm = t >> 4, tn = t & 15;

    __shared__ __align__(16) float As[64 * 34];
    __shared__ __align__(16) float Bs[64 * 36];
    __shared__ float linv[TT];

    #pragma unroll
    for (int s = 0; s < 2; ++s) {
        int qq = t + 256 * s;
        float sum = 0.f;
        #pragma unroll
        for (int pb = 0; pb < 16; ++pb) sum += lpart[((long)b * 16 + pb) * TT + qq];
        linv[qq] = __builtin_amdgcn_rcpf(sum);
    }
    __syncthreads();

    const float* Ab = ebuf + ((long)b * TT + m0) * TT;
    const float* Bb = qin + (long)b * TT * DD + n0;

    const int ara = t >> 4, aca = (t & 15) * 4;
    const int brb = t >> 3, bcb = (t & 7) * 4;

    float4 av0 = *(const float4*)(Ab + (long)ara * TT + aca);
    float4 av1 = *(const float4*)(Ab + (long)(ara + 16) * TT + aca);
    float4 bv0 = *(const float4*)(Bb + (long)brb * DD + bcb);
    float4 bv1 = *(const float4*)(Bb + (long)(brb + 32) * DD + bcb);

    float acc[2][2] = {};

    for (int c = 0; c < 8; ++c) {
        const int k0 = c * 64;
        As[(aca + 0) * 34 + ara] = av0.x;
        As[(aca + 1) * 34 + ara] = av0.y;
        As[(aca + 2) * 34 + ara] = av0.z;
        As[(aca + 3) * 34 + ara] = av0.w;
        As[(aca + 0) * 34 + ara + 16] = av1.x;
        As[(aca + 1) * 34 + ara + 16] = av1.y;
        As[(aca + 2) * 34 + ara + 16] = av1.z;
        As[(aca + 3) * 34 + ara + 16] = av1.w;
        {
            float s0 = linv[k0 + brb], s1 = linv[k0 + brb + 32];
            float4 w0, w1;
            w0.x = bv0.x * s0; w0.y = bv0.y * s0; w0.z = bv0.z * s0; w0.w = bv0.w * s0;
            w1.x = bv1.x * s1; w1.y = bv1.y * s1; w1.z = bv1.z * s1; w1.w = bv1.w * s1;
            *(float4*)&Bs[brb * 36 + bcb]        = w0;
            *(float4*)&Bs[(brb + 32) * 36 + bcb] = w1;
        }
        __syncthreads();
        if (c < 7) {
            int k1 = (c + 1) * 64;
            av0 = *(const float4*)(Ab + (long)ara * TT + k1 + aca);
            av1 = *(const float4*)(Ab + (long)(ara + 16) * TT + k1 + aca);
            bv0 = *(const float4*)(Bb + (long)(k1 + brb) * DD + bcb);
            bv1 = *(const float4*)(Bb + (long)(k1 + brb + 32) * DD + bcb);
        }
        #pragma unroll
        for (int kk = 0; kk < 64; ++kk) {
            float2 a = *(const float2*)&As[kk * 34 + 2 * tm];
            float2 bb = *(const float2*)&Bs[kk * 36 + 2 * tn];
            acc[0][0] = __builtin_fmaf(a.x, bb.x, acc[0][0]);
            acc[0][1] = __builtin_fmaf(a.x, bb.y, acc[0][1]);
            acc[1][0] = __builtin_fmaf(a.y, bb.x, acc[1][0]);
            acc[1][1] = __builtin_fmaf(a.y, bb.y, acc[1][1]);
        }
        __syncthreads();
    }

    #pragma unroll
    for (int i = 0; i < 2; ++i) {
        float2 v = make_float2(acc[i][0], acc[i][1]);
        *(float2*)(out + ((long)b * TT + m0 + 2 * tm + i) * DD + n0 + 2 * tn) = v;
    }
}

extern "C" void kernel_launch(void* const* d_in, const int* in_sizes, int n_in,
                              void* d_out, int out_size, void* d_ws, size_t ws_size,
                              hipStream_t stream) {
    const float* q  = (const float*)d_in[0];
    const float* p  = (const float*)d_in[1];
    const float* W0 = (const float*)d_in[2];
    const float* W1 = (const float*)d_in[3];
    const float* vc = (const float*)d_in[4];
    float* out = (float*)d_out;

    float* ws    = (float*)d_ws;
    float* expQ  = ws;                // [4][256][512]
    float* expP  = ws + 524288;
    float* ebuf  = ws + 1048576;      // [4][512][512]
    float* lpart = ws + 2097152;      // [4][16][512]

    proj_exp_kernel<<<dim3(512), 256, 0, stream>>>(q, p, W0, W1, expQ, expP);
    score_kernel<<<dim3(8, 16, NB), 512, 0, stream>>>(expP, expQ, vc, ebuf, lpart);
    out_kernel<<<dim3(8, 16, NB), 256, 0, stream>>>(ebuf, q, lpart, out);
}

// Round 5
// 125.644 us; speedup vs baseline: 1.5972x; 1.0229x over previous
//
#include <hip/hip_runtime.h>

#define NB 4
#define TT 512          // TQ = TP
#define DD 256
#define K2L2E    2.885390081777927f     // 2*log2(e): e^{2x} = 2^{K*x}
#define NEG2L2E (-2.885390081777927f)

#if defined(__has_builtin)
# if __has_builtin(__builtin_amdgcn_global_load_lds)
#  define HAS_GLL 1
# endif
#endif

typedef float v2f __attribute__((ext_vector_type(2)));

__device__ __forceinline__ v2f pk_fma(v2f a, v2f b, v2f c) {
#if defined(__has_builtin)
# if __has_builtin(__builtin_elementwise_fma)
    return __builtin_elementwise_fma(a, b, c);
# else
    v2f r; r.x = __builtin_fmaf(a.x, b.x, c.x); r.y = __builtin_fmaf(a.y, b.y, c.y); return r;
# endif
#else
    v2f r; r.x = __builtin_fmaf(a.x, b.x, c.x); r.y = __builtin_fmaf(a.y, b.y, c.y); return r;
#endif
}
__device__ __forceinline__ v2f splat2(float s) { v2f r; r.x = s; r.y = s; return r; }

__device__ __forceinline__ void stage16(const float* __restrict__ g, float* l) {
#ifdef HAS_GLL
    __builtin_amdgcn_global_load_lds((const __attribute__((address_space(1))) void*)g,
                                     (__attribute__((address_space(3))) void*)l, 16, 0, 0);
#else
    *(float4*)l = *(const float4*)g;
#endif
}

// ============ P1: projections + exp epilogue ============
// expQ[b][d][q] = 2^(K2L2E * (q@W0)[q,d]) = e^{2*pq};  expP likewise from p@W1.
__global__ __launch_bounds__(256) void proj_exp_kernel(
    const float* __restrict__ qin, const float* __restrict__ pin,
    const float* __restrict__ W0, const float* __restrict__ W1,
    float* __restrict__ expQ, float* __restrict__ expP)
{
    const int blk = blockIdx.x;
    const int wh = blk >> 8, tid = blk & 255;
    const int m0 = (tid >> 2) * 32, n0 = (tid & 3) * 64;
    const float* A = wh ? pin : qin;
    const float* W = wh ? W1 : W0;
    float* OUT     = wh ? expP : expQ;

    __shared__ __align__(16) float As[32 * 34];   // [k][m]
    __shared__ __align__(16) float Bs[32 * 64];   // [k][n]

    const int t  = threadIdx.x;
    const int ar = t >> 3, ac4 = (t & 7) * 4;
    const int br = t >> 4, bc4 = (t & 15) * 4;
    const int tn = t >> 4, tm = t & 15;

    const float* Ap = A + (long)(m0 + ar) * DD + ac4;

    float4 av  = *(const float4*)Ap;
    float4 bv0 = *(const float4*)(W + (long)br * DD + n0 + bc4);
    float4 bv1 = *(const float4*)(W + (long)(br + 16) * DD + n0 + bc4);

    float acc[2][4] = {};

    for (int c = 0; c < 8; ++c) {
        As[(ac4 + 0) * 34 + ar] = av.x;
        As[(ac4 + 1) * 34 + ar] = av.y;
        As[(ac4 + 2) * 34 + ar] = av.z;
        As[(ac4 + 3) * 34 + ar] = av.w;
        *(float4*)&Bs[br * 64 + bc4]        = bv0;
        *(float4*)&Bs[(br + 16) * 64 + bc4] = bv1;
        __syncthreads();
        if (c < 7) {
            int k1 = (c + 1) * 32;
            av  = *(const float4*)(Ap + k1);
            bv0 = *(const float4*)(W + (long)(k1 + br) * DD + n0 + bc4);
            bv1 = *(const float4*)(W + (long)(k1 + 16 + br) * DD + n0 + bc4);
        }
        #pragma unroll
        for (int kk = 0; kk < 32; ++kk) {
            float2 a = *(const float2*)&As[kk * 34 + 2 * tm];
            float4 b = *(const float4*)&Bs[kk * 64 + 4 * tn];
            float aa[2] = {a.x, a.y};
            float bb[4] = {b.x, b.y, b.z, b.w};
            #pragma unroll
            for (int i = 0; i < 2; ++i)
                #pragma unroll
                for (int j = 0; j < 4; ++j)
                    acc[i][j] = __builtin_fmaf(aa[i], bb[j], acc[i][j]);
        }
        __syncthreads();
    }

    const int  bi = m0 >> 9;
    const int  ml = (m0 & 511) + 2 * tm;
    #pragma unroll
    for (int j = 0; j < 4; ++j) {
        int d = n0 + 4 * tn + j;
        float2 st;
        st.x = __builtin_amdgcn_exp2f(acc[0][j] * K2L2E);
        st.y = __builtin_amdgcn_exp2f(acc[1][j] * K2L2E);
        *(float2*)(OUT + ((long)bi * DD + d) * TT + ml) = st;
    }
}

// ============ P2: scores ============
// 32p x 64q tile, 512 thr, 2p x 2q microtile (q packed as v2f -> v_pk_*_f32),
// d-chunk 64, async dbuf. Inner: E = EA*EB, pair-rcp identity.
__global__ __launch_bounds__(512, 4) void score_kernel(
    const float* __restrict__ expP, const float* __restrict__ expQ,
    const float* __restrict__ vc, float* __restrict__ ebuf, float* __restrict__ lpart)
{
    const int b = blockIdx.z, pt = blockIdx.y, qt = blockIdx.x;
    const int p0 = pt * 32, q0 = qt * 64;
    const int t  = threadIdx.x;
    const int qx = t & 31, py = t >> 5;          // q = q0+2qx+{0,1}, p = p0+2py+{0,1}

    __shared__ __align__(16) float PA[2][64 * 32];   // [d][p]
    __shared__ __align__(16) float QB[2][64 * 64];   // [d][q]
    __shared__ float vcs[DD];

    const float* gP = expP + (long)b * DD * TT + p0;
    const float* gQ = expQ + (long)b * DD * TT + q0;

    {
        int d = t >> 3, off = (t & 7) * 4;
        stage16(gP + (long)d * TT + off, &PA[0][t * 4]);
    }
    #pragma unroll
    for (int s = 0; s < 2; ++s) {
        int f = t + 512 * s, d = f >> 4, off = (f & 15) * 4;
        stage16(gQ + (long)d * TT + off, &QB[0][f * 4]);
    }
    if (t < DD) vcs[t] = vc[t];
    __syncthreads();

    v2f acc[2]; acc[0] = splat2(0.f); acc[1] = splat2(0.f);

    for (int c = 0; c < 4; ++c) {
        if (c < 3) {
            int dc = (c + 1) * 64, nb = (c + 1) & 1;
            {
                int d = t >> 3, off = (t & 7) * 4;
                stage16(gP + (long)(dc + d) * TT + off, &PA[nb][t * 4]);
            }
            #pragma unroll
            for (int s = 0; s < 2; ++s) {
                int f = t + 512 * s, d = f >> 4, off = (f & 15) * 4;
                stage16(gQ + (long)(dc + d) * TT + off, &QB[nb][f * 4]);
            }
        }
        const float* PAc = PA[c & 1];
        const float* QBc = QB[c & 1];
        const float* vcb = &vcs[c * 64];
        #pragma unroll 8
        for (int dp = 0; dp < 32; ++dp) {
            float2 vp = *(const float2*)&vcb[2 * dp];
            v2f vsv = splat2(vp.x + vp.y);
            v2f vx  = splat2(vp.x), vy = splat2(vp.y);
            float2 A0 = *(const float2*)&PAc[(2 * dp) * 32 + 2 * py];
            float2 A1 = *(const float2*)&PAc[(2 * dp + 1) * 32 + 2 * py];
            v2f B0 = *(const v2f*)&QBc[(2 * dp) * 64 + 2 * qx];
            v2f B1 = *(const v2f*)&QBc[(2 * dp + 1) * 64 + 2 * qx];
            float a0[2] = {A0.x, A0.y}, a1[2] = {A1.x, A1.y};
            #pragma unroll
            for (int i = 0; i < 2; ++i) {
                v2f E0  = splat2(a0[i]) * B0;                 // pk_mul
                v2f E1  = splat2(a1[i]) * B1;                 // pk_mul
                v2f u   = (E0 + E1) + 1.0f;                   // 2x pk_add
                v2f den = pk_fma(E0, E1, u);                  // (1+E0)(1+E1)
                v2f num = pk_fma(vy, E0, pk_fma(vx, E1, vsv));
                v2f r;
                r.x = __builtin_amdgcn_rcpf(den.x);
                r.y = __builtin_amdgcn_rcpf(den.y);
                acc[i] = pk_fma(num, r, acc[i]);
            }
        }
        __syncthreads();
    }

    // e = exp2(NEG2L2E * acc); write + per-block column partial sums
    float* eb = ebuf + ((long)b * TT + p0) * TT + q0;
    v2f colp = splat2(0.f);
    #pragma unroll
    for (int i = 0; i < 2; ++i) {
        float2 ev;
        ev.x = __builtin_amdgcn_exp2f(acc[i].x * NEG2L2E);
        ev.y = __builtin_amdgcn_exp2f(acc[i].y * NEG2L2E);
        *(float2*)(eb + (long)(2 * py + i) * TT + 2 * qx) = ev;
        colp.x += ev.x; colp.y += ev.y;
    }
    float* scr = (float*)&PA[0][0];
    *(float2*)&scr[py * 64 + 2 * qx] = make_float2(colp.x, colp.y);
    __syncthreads();
    if (t < 64) {
        float s = 0.f;
        #pragma unroll
        for (int r = 0; r < 16; ++r) s += scr[r * 64 + t];
        lpart[((long)b * 16 + pt) * TT + q0 + t] = s;
    }
}

// ============ P3: out[b,p,:] = sum_q (e[p,q]/l[q]) * qin[b,q,:] ============
// 32p x 32d tile, 128 thr, 4p x 2d microtile (b128 A reads, packed FMA),
// K-chunk 64, reg-prefetch double buffer. 512 blocks.
__global__ __launch_bounds__(128) void out_kernel(
    const float* __restrict__ ebuf, const float* __restrict__ qin,
    const float* __restrict__ lpart, float* __restrict__ out)
{
    const int b = blockIdx.z, pt = blockIdx.y, dt = blockIdx.x;
    const int m0 = pt * 32, n0 = dt * 32;
    const int t  = threadIdx.x;                 // 0..127
    const int tm = t >> 4;                      // 0..7  -> p = 4*tm + i
    const int tn = t & 15;                      // d = 2*tn + j

    __shared__ __align__(16) float As[64 * 36]; // [k][p], pad 36
    __shared__ __align__(16) float Bs[64 * 36]; // [k][d], rows pre-scaled by linv[k]
    __shared__ float linv[TT];

    #pragma unroll
    for (int s = 0; s < 4; ++s) {
        int qq = t + 128 * s;
        float sum = 0.f;
        #pragma unroll
        for (int pb = 0; pb < 16; ++pb) sum += lpart[((long)b * 16 + pb) * TT + qq];
        linv[qq] = __builtin_amdgcn_rcpf(sum);
    }
    __syncthreads();

    const float* Ab = ebuf + ((long)b * TT + m0) * TT;   // 32 p-rows x 512 k
    const float* Bb = qin + (long)b * TT * DD + n0;      // 512 k-rows x 32 d

    const int ar  = t >> 2;            // A stage: p row 0..31
    const int akc = (t & 3) * 4;       // A k sub-offset; quads at 16u + akc
    const int brr = t >> 3;            // B stage: k row 0..15 (+16u)
    const int bc4 = (t & 7) * 4;       // B d col

    float4 av[4], bv[4];
    #pragma unroll
    for (int u = 0; u < 4; ++u) {
        av[u] = *(const float4*)(Ab + (long)ar * TT + 16 * u + akc);
        bv[u] = *(const float4*)(Bb + (long)(brr + 16 * u) * DD + bc4);
    }

    v2f acc[4]; acc[0] = splat2(0.f); acc[1] = splat2(0.f);
    acc[2] = splat2(0.f); acc[3] = splat2(0.f);

    for (int c = 0; c < 8; ++c) {
        const int k0 = c * 64;
        #pragma unroll
        for (int u = 0; u < 4; ++u) {
            int kl = 16 * u + akc;
            As[(kl + 0) * 36 + ar] = av[u].x;
            As[(kl + 1) * 36 + ar] = av[u].y;
            As[(kl + 2) * 36 + ar] = av[u].z;
            As[(kl + 3) * 36 + ar] = av[u].w;
            float s = linv[k0 + brr + 16 * u];
            float4 w;
            w.x = bv[u].x * s; w.y = bv[u].y * s; w.z = bv[u].z * s; w.w = bv[u].w * s;
            *(float4*)&Bs[(brr + 16 * u) * 36 + bc4] = w;
        }
        __syncthreads();
        if (c < 7) {
            int k1 = (c + 1) * 64;
            #pragma unroll
            for (int u = 0; u < 4; ++u) {
                av[u] = *(const float4*)(Ab + (long)ar * TT + k1 + 16 * u + akc);
                bv[u] = *(const float4*)(Bb + (long)(k1 + brr + 16 * u) * DD + bc4);
            }
        }
        #pragma unroll
        for (int kk = 0; kk < 64; ++kk) {
            float4 a = *(const float4*)&As[kk * 36 + 4 * tm];
            v2f bb = *(const v2f*)&Bs[kk * 36 + 2 * tn];
            acc[0] = pk_fma(splat2(a.x), bb, acc[0]);
            acc[1] = pk_fma(splat2(a.y), bb, acc[1]);
            acc[2] = pk_fma(splat2(a.z), bb, acc[2]);
            acc[3] = pk_fma(splat2(a.w), bb, acc[3]);
        }
        __syncthreads();
    }

    #pragma unroll
    for (int i = 0; i < 4; ++i) {
        *(float2*)(out + ((long)b * TT + m0 + 4 * tm + i) * DD + n0 + 2 * tn) =
            make_float2(acc[i].x, acc[i].y);
    }
}

extern "C" void kernel_launch(void* const* d_in, const int* in_sizes, int n_in,
                              void* d_out, int out_size, void* d_ws, size_t ws_size,
                              hipStream_t stream) {
    const float* q  = (const float*)d_in[0];
    const float* p  = (const float*)d_in[1];
    const float* W0 = (const float*)d_in[2];
    const float* W1 = (const float*)d_in[3];
    const float* vc = (const float*)d_in[4];
    float* out = (float*)d_out;

    float* ws    = (float*)d_ws;
    float* expQ  = ws;                // [4][256][512]
    float* expP  = ws + 524288;
    float* ebuf  = ws + 1048576;      // [4][512][512]
    float* lpart = ws + 2097152;      // [4][16][512]

    proj_exp_kernel<<<dim3(512), 256, 0, stream>>>(q, p, W0, W1, expQ, expP);
    score_kernel<<<dim3(8, 16, NB), 512, 0, stream>>>(expP, expQ, vc, ebuf, lpart);
    out_kernel<<<dim3(8, 16, NB), 128, 0, stream>>>(ebuf, q, lpart, out);
}

// Round 6
// 124.436 us; speedup vs baseline: 1.6127x; 1.0097x over previous
//
#include <hip/hip_runtime.h>

#define NB 4
#define TT 512          // TQ = TP
#define DD 256
#define K2L2E    2.885390081777927f     // 2*log2(e): e^{2x} = 2^{K*x}
#define NEG2L2E (-2.885390081777927f)

#if defined(__has_builtin)
# if __has_builtin(__builtin_amdgcn_global_load_lds)
#  define HAS_GLL 1
# endif
#endif

typedef float v2f __attribute__((ext_vector_type(2)));

__device__ __forceinline__ v2f pk_fma(v2f a, v2f b, v2f c) {
#if defined(__has_builtin)
# if __has_builtin(__builtin_elementwise_fma)
    return __builtin_elementwise_fma(a, b, c);
# else
    v2f r; r.x = __builtin_fmaf(a.x, b.x, c.x); r.y = __builtin_fmaf(a.y, b.y, c.y); return r;
# endif
#else
    v2f r; r.x = __builtin_fmaf(a.x, b.x, c.x); r.y = __builtin_fmaf(a.y, b.y, c.y); return r;
#endif
}
__device__ __forceinline__ v2f splat2(float s) { v2f r; r.x = s; r.y = s; return r; }

__device__ __forceinline__ void stage16(const float* __restrict__ g, float* l) {
#ifdef HAS_GLL
    __builtin_amdgcn_global_load_lds((const __attribute__((address_space(1))) void*)g,
                                     (__attribute__((address_space(3))) void*)l, 16, 0, 0);
#else
    *(float4*)l = *(const float4*)g;
#endif
}

// ============ P1: projections + exp epilogue ============
// expQ[b][d][q] = 2^(K2L2E * (q@W0)[q,d]) = e^{2*pq};  expP likewise from p@W1.
__global__ __launch_bounds__(256) void proj_exp_kernel(
    const float* __restrict__ qin, const float* __restrict__ pin,
    const float* __restrict__ W0, const float* __restrict__ W1,
    float* __restrict__ expQ, float* __restrict__ expP)
{
    const int blk = blockIdx.x;
    const int wh = blk >> 8, tid = blk & 255;
    const int m0 = (tid >> 2) * 32, n0 = (tid & 3) * 64;
    const float* A = wh ? pin : qin;
    const float* W = wh ? W1 : W0;
    float* OUT     = wh ? expP : expQ;

    __shared__ __align__(16) float As[32 * 34];   // [k][m]
    __shared__ __align__(16) float Bs[32 * 64];   // [k][n]

    const int t  = threadIdx.x;
    const int ar = t >> 3, ac4 = (t & 7) * 4;
    const int br = t >> 4, bc4 = (t & 15) * 4;
    const int tn = t >> 4, tm = t & 15;

    const float* Ap = A + (long)(m0 + ar) * DD + ac4;

    float4 av  = *(const float4*)Ap;
    float4 bv0 = *(const float4*)(W + (long)br * DD + n0 + bc4);
    float4 bv1 = *(const float4*)(W + (long)(br + 16) * DD + n0 + bc4);

    float acc[2][4] = {};

    for (int c = 0; c < 8; ++c) {
        As[(ac4 + 0) * 34 + ar] = av.x;
        As[(ac4 + 1) * 34 + ar] = av.y;
        As[(ac4 + 2) * 34 + ar] = av.z;
        As[(ac4 + 3) * 34 + ar] = av.w;
        *(float4*)&Bs[br * 64 + bc4]        = bv0;
        *(float4*)&Bs[(br + 16) * 64 + bc4] = bv1;
        __syncthreads();
        if (c < 7) {
            int k1 = (c + 1) * 32;
            av  = *(const float4*)(Ap + k1);
            bv0 = *(const float4*)(W + (long)(k1 + br) * DD + n0 + bc4);
            bv1 = *(const float4*)(W + (long)(k1 + 16 + br) * DD + n0 + bc4);
        }
        #pragma unroll
        for (int kk = 0; kk < 32; ++kk) {
            float2 a = *(const float2*)&As[kk * 34 + 2 * tm];
            float4 b = *(const float4*)&Bs[kk * 64 + 4 * tn];
            float aa[2] = {a.x, a.y};
            float bb[4] = {b.x, b.y, b.z, b.w};
            #pragma unroll
            for (int i = 0; i < 2; ++i)
                #pragma unroll
                for (int j = 0; j < 4; ++j)
                    acc[i][j] = __builtin_fmaf(aa[i], bb[j], acc[i][j]);
        }
        __syncthreads();
    }

    const int  bi = m0 >> 9;
    const int  ml = (m0 & 511) + 2 * tm;
    #pragma unroll
    for (int j = 0; j < 4; ++j) {
        int d = n0 + 4 * tn + j;
        float2 st;
        st.x = __builtin_amdgcn_exp2f(acc[0][j] * K2L2E);
        st.y = __builtin_amdgcn_exp2f(acc[1][j] * K2L2E);
        *(float2*)(OUT + ((long)bi * DD + d) * TT + ml) = st;
    }
}

// ============ P2: scores ============
// 32p x 64q tile, 512 thr, 2p x 2q-pk microtile. d staged in TWO 128-deep
// chunks, NO double buffer: LDS 49.4 KB -> 3 blocks/CU -> 6 waves/SIMD.
// Only 2 vmcnt-drain barriers per block; staggered blocks hide them.
__global__ __launch_bounds__(512, 6) void score_kernel(
    const float* __restrict__ expP, const float* __restrict__ expQ,
    const float* __restrict__ vc, float* __restrict__ ebuf, float* __restrict__ lpart)
{
    const int b = blockIdx.z, pt = blockIdx.y, qt = blockIdx.x;
    const int p0 = pt * 32, q0 = qt * 64;
    const int t  = threadIdx.x;
    const int qx = t & 31, py = t >> 5;          // q = q0+2qx+{0,1}, p = p0+2py+{0,1}

    __shared__ __align__(16) float PA[128 * 32];   // [d][p] 16 KB
    __shared__ __align__(16) float QB[128 * 64];   // [d][q] 32 KB
    __shared__ float vcs[DD];

    const float* gP = expP + (long)b * DD * TT + p0;
    const float* gQ = expQ + (long)b * DD * TT + q0;

    // ---- stage chunk 0 (d = 0..127): P 1024 f4 (2/thr), Q 2048 f4 (4/thr)
    #pragma unroll
    for (int s = 0; s < 2; ++s) {
        int f = t + 512 * s, d = f >> 3, off = (f & 7) * 4;
        stage16(gP + (long)d * TT + off, &PA[f * 4]);
    }
    #pragma unroll
    for (int s = 0; s < 4; ++s) {
        int f = t + 512 * s, d = f >> 4, off = (f & 15) * 4;
        stage16(gQ + (long)d * TT + off, &QB[f * 4]);
    }
    if (t < DD) vcs[t] = vc[t];
    __syncthreads();

    v2f acc[2]; acc[0] = splat2(0.f); acc[1] = splat2(0.f);

    for (int c = 0; c < 2; ++c) {
        if (c == 1) {
            __syncthreads();   // everyone done reading chunk 0
            #pragma unroll
            for (int s = 0; s < 2; ++s) {
                int f = t + 512 * s, d = f >> 3, off = (f & 7) * 4;
                stage16(gP + (long)(128 + d) * TT + off, &PA[f * 4]);
            }
            #pragma unroll
            for (int s = 0; s < 4; ++s) {
                int f = t + 512 * s, d = f >> 4, off = (f & 15) * 4;
                stage16(gQ + (long)(128 + d) * TT + off, &QB[f * 4]);
            }
            __syncthreads();   // drain staging
        }
        const float* vcb = &vcs[c * 128];
        #pragma unroll 8
        for (int dp = 0; dp < 64; ++dp) {
            float2 vp = *(const float2*)&vcb[2 * dp];
            v2f vsv = splat2(vp.x + vp.y);
            v2f vx  = splat2(vp.x), vy = splat2(vp.y);
            float2 A0 = *(const float2*)&PA[(2 * dp) * 32 + 2 * py];
            float2 A1 = *(const float2*)&PA[(2 * dp + 1) * 32 + 2 * py];
            v2f B0 = *(const v2f*)&QB[(2 * dp) * 64 + 2 * qx];
            v2f B1 = *(const v2f*)&QB[(2 * dp + 1) * 64 + 2 * qx];
            float a0[2] = {A0.x, A0.y}, a1[2] = {A1.x, A1.y};
            #pragma unroll
            for (int i = 0; i < 2; ++i) {
                v2f E0  = splat2(a0[i]) * B0;                 // pk_mul
                v2f E1  = splat2(a1[i]) * B1;                 // pk_mul
                v2f u   = (E0 + E1) + 1.0f;                   // 2x pk_add
                v2f den = pk_fma(E0, E1, u);                  // (1+E0)(1+E1)
                v2f num = pk_fma(vy, E0, pk_fma(vx, E1, vsv));
                v2f r;
                r.x = __builtin_amdgcn_rcpf(den.x);
                r.y = __builtin_amdgcn_rcpf(den.y);
                acc[i] = pk_fma(num, r, acc[i]);
            }
        }
    }

    // e = exp2(NEG2L2E * acc); write + per-block column partial sums
    float* eb = ebuf + ((long)b * TT + p0) * TT + q0;
    v2f colp = splat2(0.f);
    #pragma unroll
    for (int i = 0; i < 2; ++i) {
        float2 ev;
        ev.x = __builtin_amdgcn_exp2f(acc[i].x * NEG2L2E);
        ev.y = __builtin_amdgcn_exp2f(acc[i].y * NEG2L2E);
        *(float2*)(eb + (long)(2 * py + i) * TT + 2 * qx) = ev;
        colp.x += ev.x; colp.y += ev.y;
    }
    __syncthreads();                 // all reads of PA done before reuse
    float* scr = (float*)&PA[0];
    *(float2*)&scr[py * 64 + 2 * qx] = make_float2(colp.x, colp.y);
    __syncthreads();
    if (t < 64) {
        float s = 0.f;
        #pragma unroll
        for (int r = 0; r < 16; ++r) s += scr[r * 64 + t];
        lpart[((long)b * 16 + pt) * TT + q0 + t] = s;
    }
}

// ============ P3: out[b,p,:] = sum_q (e[p,q]/l[q]) * qin[b,q,:] ============
// 32p x 32d tile, 128 thr, 4p x 2d microtile (b128 A reads, packed FMA),
// K-chunk 64, reg-prefetch double buffer. 512 blocks.
__global__ __launch_bounds__(128) void out_kernel(
    const float* __restrict__ ebuf, const float* __restrict__ qin,
    const float* __restrict__ lpart, float* __restrict__ out)
{
    const int b = blockIdx.z, pt = blockIdx.y, dt = blockIdx.x;
    const int m0 = pt * 32, n0 = dt * 32;
    const int t  = threadIdx.x;                 // 0..127
    const int tm = t >> 4;                      // 0..7  -> p = 4*tm + i
    const int tn = t & 15;                      // d = 2*tn + j

    __shared__ __align__(16) float As[64 * 36]; // [k][p], pad 36
    __shared__ __align__(16) float Bs[64 * 36]; // [k][d], rows pre-scaled by linv[k]
    __shared__ float linv[TT];

    #pragma unroll
    for (int s = 0; s < 4; ++s) {
        int qq = t + 128 * s;
        float sum = 0.f;
        #pragma unroll
        for (int pb = 0; pb < 16; ++pb) sum += lpart[((long)b * 16 + pb) * TT + qq];
        linv[qq] = __builtin_amdgcn_rcpf(sum);
    }
    __syncthreads();

    const float* Ab = ebuf + ((long)b * TT + m0) * TT;   // 32 p-rows x 512 k
    const float* Bb = qin + (long)b * TT * DD + n0;      // 512 k-rows x 32 d

    const int ar  = t >> 2;            // A stage: p row 0..31
    const int akc = (t & 3) * 4;       // A k sub-offset; quads at 16u + akc
    const int brr = t >> 3;            // B stage: k row 0..15 (+16u)
    const int bc4 = (t & 7) * 4;       // B d col

    float4 av[4], bv[4];
    #pragma unroll
    for (int u = 0; u < 4; ++u) {
        av[u] = *(const float4*)(Ab + (long)ar * TT + 16 * u + akc);
        bv[u] = *(const float4*)(Bb + (long)(brr + 16 * u) * DD + bc4);
    }

    v2f acc[4]; acc[0] = splat2(0.f); acc[1] = splat2(0.f);
    acc[2] = splat2(0.f); acc[3] = splat2(0.f);

    for (int c = 0; c < 8; ++c) {
        const int k0 = c * 64;
        #pragma unroll
        for (int u = 0; u < 4; ++u) {
            int kl = 16 * u + akc;
            As[(kl + 0) * 36 + ar] = av[u].x;
            As[(kl + 1) * 36 + ar] = av[u].y;
            As[(kl + 2) * 36 + ar] = av[u].z;
            As[(kl + 3) * 36 + ar] = av[u].w;
            float s = linv[k0 + brr + 16 * u];
            float4 w;
            w.x = bv[u].x * s; w.y = bv[u].y * s; w.z = bv[u].z * s; w.w = bv[u].w * s;
            *(float4*)&Bs[(brr + 16 * u) * 36 + bc4] = w;
        }
        __syncthreads();
        if (c < 7) {
            int k1 = (c + 1) * 64;
            #pragma unroll
            for (int u = 0; u < 4; ++u) {
                av[u] = *(const float4*)(Ab + (long)ar * TT + k1 + 16 * u + akc);
                bv[u] = *(const float4*)(Bb + (long)(k1 + brr + 16 * u) * DD + bc4);
            }
        }
        #pragma unroll
        for (int kk = 0; kk < 64; ++kk) {
            float4 a = *(const float4*)&As[kk * 36 + 4 * tm];
            v2f bb = *(const v2f*)&Bs[kk * 36 + 2 * tn];
            acc[0] = pk_fma(splat2(a.x), bb, acc[0]);
            acc[1] = pk_fma(splat2(a.y), bb, acc[1]);
            acc[2] = pk_fma(splat2(a.z), bb, acc[2]);
            acc[3] = pk_fma(splat2(a.w), bb, acc[3]);
        }
        __syncthreads();
    }

    #pragma unroll
    for (int i = 0; i < 4; ++i) {
        *(float2*)(out + ((long)b * TT + m0 + 4 * tm + i) * DD + n0 + 2 * tn) =
            make_float2(acc[i].x, acc[i].y);
    }
}

extern "C" void kernel_launch(void* const* d_in, const int* in_sizes, int n_in,
                              void* d_out, int out_size, void* d_ws, size_t ws_size,
                              hipStream_t stream) {
    const float* q  = (const float*)d_in[0];
    const float* p  = (const float*)d_in[1];
    const float* W0 = (const float*)d_in[2];
    const float* W1 = (const float*)d_in[3];
    const float* vc = (const float*)d_in[4];
    float* out = (float*)d_out;

    float* ws    = (float*)d_ws;
    float* expQ  = ws;                // [4][256][512]
    float* expP  = ws + 524288;
    float* ebuf  = ws + 1048576;      // [4][512][512]
    float* lpart = ws + 2097152;      // [4][16][512]

    proj_exp_kernel<<<dim3(512), 256, 0, stream>>>(q, p, W0, W1, expQ, expP);
    score_kernel<<<dim3(8, 16, NB), 512, 0, stream>>>(expP, expQ, vc, ebuf, lpart);
    out_kernel<<<dim3(8, 16, NB), 128, 0, stream>>>(ebuf, q, lpart, out);
}

// Round 7
// 123.756 us; speedup vs baseline: 1.6215x; 1.0055x over previous
//
#include <hip/hip_runtime.h>

#define NB 4
#define TT 512          // TQ = TP
#define DD 256
#define K2L2E    2.885390081777927f     // 2*log2(e): e^{2x} = 2^{K*x}
#define NEG2L2E (-2.885390081777927f)

#if defined(__has_builtin)
# if __has_builtin(__builtin_amdgcn_global_load_lds)
#  define HAS_GLL 1
# endif
#endif

typedef float v2f __attribute__((ext_vector_type(2)));

__device__ __forceinline__ v2f pk_fma(v2f a, v2f b, v2f c) {
#if defined(__has_builtin)
# if __has_builtin(__builtin_elementwise_fma)
    return __builtin_elementwise_fma(a, b, c);
# else
    v2f r; r.x = __builtin_fmaf(a.x, b.x, c.x); r.y = __builtin_fmaf(a.y, b.y, c.y); return r;
# endif
#else
    v2f r; r.x = __builtin_fmaf(a.x, b.x, c.x); r.y = __builtin_fmaf(a.y, b.y, c.y); return r;
#endif
}
__device__ __forceinline__ v2f splat2(float s) { v2f r; r.x = s; r.y = s; return r; }

__device__ __forceinline__ void stage16(const float* __restrict__ g, float* l) {
#ifdef HAS_GLL
    __builtin_amdgcn_global_load_lds((const __attribute__((address_space(1))) void*)g,
                                     (__attribute__((address_space(3))) void*)l, 16, 0, 0);
#else
    *(float4*)l = *(const float4*)g;
#endif
}

// ============ P1: projections + exp epilogue ============
// expQ[b][d][q] = e^{2*(q@W0)[q,d]}  (TRANSPOSED, q-minor)
// expP[b][p][d] = e^{2*(p@W1)[p,d]}  (NATURAL, d-minor)
__global__ __launch_bounds__(256) void proj_exp_kernel(
    const float* __restrict__ qin, const float* __restrict__ pin,
    const float* __restrict__ W0, const float* __restrict__ W1,
    float* __restrict__ expQ, float* __restrict__ expP)
{
    const int blk = blockIdx.x;
    const int wh = blk >> 8, tid = blk & 255;
    const int m0 = (tid >> 2) * 32, n0 = (tid & 3) * 64;
    const float* A = wh ? pin : qin;
    const float* W = wh ? W1 : W0;

    __shared__ __align__(16) float As[32 * 34];   // [k][m]
    __shared__ __align__(16) float Bs[32 * 64];   // [k][n]

    const int t  = threadIdx.x;
    const int ar = t >> 3, ac4 = (t & 7) * 4;
    const int br = t >> 4, bc4 = (t & 15) * 4;
    // microtile index roles swap per output orientation (store-coalescing)
    const int tm = wh ? (t >> 4) : (t & 15);
    const int tn = wh ? (t & 15) : (t >> 4);

    const float* Ap = A + (long)(m0 + ar) * DD + ac4;

    float4 av  = *(const float4*)Ap;
    float4 bv0 = *(const float4*)(W + (long)br * DD + n0 + bc4);
    float4 bv1 = *(const float4*)(W + (long)(br + 16) * DD + n0 + bc4);

    float acc[2][4] = {};

    for (int c = 0; c < 8; ++c) {
        As[(ac4 + 0) * 34 + ar] = av.x;
        As[(ac4 + 1) * 34 + ar] = av.y;
        As[(ac4 + 2) * 34 + ar] = av.z;
        As[(ac4 + 3) * 34 + ar] = av.w;
        *(float4*)&Bs[br * 64 + bc4]        = bv0;
        *(float4*)&Bs[(br + 16) * 64 + bc4] = bv1;
        __syncthreads();
        if (c < 7) {
            int k1 = (c + 1) * 32;
            av  = *(const float4*)(Ap + k1);
            bv0 = *(const float4*)(W + (long)(k1 + br) * DD + n0 + bc4);
            bv1 = *(const float4*)(W + (long)(k1 + 16 + br) * DD + n0 + bc4);
        }
        #pragma unroll
        for (int kk = 0; kk < 32; ++kk) {
            float2 a = *(const float2*)&As[kk * 34 + 2 * tm];
            float4 b = *(const float4*)&Bs[kk * 64 + 4 * tn];
            float aa[2] = {a.x, a.y};
            float bb[4] = {b.x, b.y, b.z, b.w};
            #pragma unroll
            for (int i = 0; i < 2; ++i)
                #pragma unroll
                for (int j = 0; j < 4; ++j)
                    acc[i][j] = __builtin_fmaf(aa[i], bb[j], acc[i][j]);
        }
        __syncthreads();
    }

    const int bi = m0 >> 9;
    const int ml = m0 & 511;
    if (wh) {
        // natural: expP[bi][ml+2tm+i][n0+4tn .. +3], float4 store, tn-minor lanes
        #pragma unroll
        for (int i = 0; i < 2; ++i) {
            float4 st;
            st.x = __builtin_amdgcn_exp2f(acc[i][0] * K2L2E);
            st.y = __builtin_amdgcn_exp2f(acc[i][1] * K2L2E);
            st.z = __builtin_amdgcn_exp2f(acc[i][2] * K2L2E);
            st.w = __builtin_amdgcn_exp2f(acc[i][3] * K2L2E);
            *(float4*)(expP + ((long)bi * TT + ml + 2 * tm + i) * DD + n0 + 4 * tn) = st;
        }
    } else {
        // transposed: expQ[bi][n0+4tn+j][ml+2tm .. +1], float2 store, tm-minor lanes
        #pragma unroll
        for (int j = 0; j < 4; ++j) {
            int d = n0 + 4 * tn + j;
            float2 st;
            st.x = __builtin_amdgcn_exp2f(acc[0][j] * K2L2E);
            st.y = __builtin_amdgcn_exp2f(acc[1][j] * K2L2E);
            *(float2*)(expQ + ((long)bi * DD + d) * TT + ml + 2 * tm) = st;
        }
    }
}

// ============ P2: scores ============
// 32p x 64q tile, 512 thr, 2p x 2q-pk microtile, d-quad rcp batching:
//   sum_{k=0..3} v_k/(1+E_k) = (n01*t23 + n23*t01) * rcp(t01*t23)
// PA natural [p][d] (b128 A reads), QB [d][q]. Two 128-d chunks, no dbuf,
// 49.4 KB LDS -> 3 blocks/CU -> 6 waves/SIMD.
__global__ __launch_bounds__(512, 6) void score_kernel(
    const float* __restrict__ expP, const float* __restrict__ expQ,
    const float* __restrict__ vc, float* __restrict__ ebuf, float* __restrict__ lpart)
{
    const int b = blockIdx.z, pt = blockIdx.y, qt = blockIdx.x;
    const int p0 = pt * 32, q0 = qt * 64;
    const int t  = threadIdx.x;
    const int qx = t & 31, py = t >> 5;          // q = q0+2qx+{0,1}, p = p0+2py+{0,1}

    __shared__ __align__(16) float PA[32 * 128];   // [p][d-chunk] 16 KB
    __shared__ __align__(16) float QB[128 * 64];   // [d][q] 32 KB
    __shared__ __align__(16) float vcs[DD];

    const float* gP = expP + ((long)b * TT + p0) * DD;   // natural [p][d]
    const float* gQ = expQ + (long)b * DD * TT + q0;     // [d][q]

    // ---- stage chunk 0 (d = 0..127)
    #pragma unroll
    for (int s = 0; s < 2; ++s) {
        int f = t + 512 * s, pr = f >> 5, d4 = (f & 31) * 4;
        stage16(gP + (long)pr * DD + d4, &PA[f * 4]);
    }
    #pragma unroll
    for (int s = 0; s < 4; ++s) {
        int f = t + 512 * s, d = f >> 4, o4 = (f & 15) * 4;
        stage16(gQ + (long)d * TT + o4, &QB[f * 4]);
    }
    if (t < DD) vcs[t] = vc[t];
    __syncthreads();

    v2f acc[2]; acc[0] = splat2(0.f); acc[1] = splat2(0.f);

    for (int c = 0; c < 2; ++c) {
        if (c == 1) {
            __syncthreads();   // chunk 0 fully consumed
            #pragma unroll
            for (int s = 0; s < 2; ++s) {
                int f = t + 512 * s, pr = f >> 5, d4 = (f & 31) * 4;
                stage16(gP + (long)pr * DD + 128 + d4, &PA[f * 4]);
            }
            #pragma unroll
            for (int s = 0; s < 4; ++s) {
                int f = t + 512 * s, d = f >> 4, o4 = (f & 15) * 4;
                stage16(gQ + (long)(128 + d) * TT + o4, &QB[f * 4]);
            }
            __syncthreads();   // drain staging
        }
        const float* vcb = &vcs[c * 128];
        #pragma unroll 4
        for (int dq = 0; dq < 32; ++dq) {
            float4 vq = *(const float4*)&vcb[4 * dq];
            float vs01 = vq.x + vq.y, vs23 = vq.z + vq.w;
            float4 aq0 = *(const float4*)&PA[(2 * py) * 128 + 4 * dq];
            float4 aq1 = *(const float4*)&PA[(2 * py + 1) * 128 + 4 * dq];
            v2f B0 = *(const v2f*)&QB[(4 * dq + 0) * 64 + 2 * qx];
            v2f B1 = *(const v2f*)&QB[(4 * dq + 1) * 64 + 2 * qx];
            v2f B2 = *(const v2f*)&QB[(4 * dq + 2) * 64 + 2 * qx];
            v2f B3 = *(const v2f*)&QB[(4 * dq + 3) * 64 + 2 * qx];
            #pragma unroll
            for (int i = 0; i < 2; ++i) {
                float4 a = i ? aq1 : aq0;
                v2f E0 = splat2(a.x) * B0;
                v2f E1 = splat2(a.y) * B1;
                v2f E2 = splat2(a.z) * B2;
                v2f E3 = splat2(a.w) * B3;
                v2f t01 = pk_fma(E0, E1, (E0 + E1) + 1.0f);   // (1+E0)(1+E1)
                v2f t23 = pk_fma(E2, E3, (E2 + E3) + 1.0f);   // (1+E2)(1+E3)
                v2f den = t01 * t23;
                v2f n01 = pk_fma(splat2(vq.x), E1, pk_fma(splat2(vq.y), E0, splat2(vs01)));
                v2f n23 = pk_fma(splat2(vq.z), E3, pk_fma(splat2(vq.w), E2, splat2(vs23)));
                v2f num = pk_fma(n01, t23, n23 * t01);
                v2f r;
                r.x = __builtin_amdgcn_rcpf(den.x);
                r.y = __builtin_amdgcn_rcpf(den.y);
                acc[i] = pk_fma(num, r, acc[i]);
            }
        }
    }

    // e = exp2(NEG2L2E * acc); write + per-block column partial sums
    float* eb = ebuf + ((long)b * TT + p0) * TT + q0;
    v2f colp = splat2(0.f);
    #pragma unroll
    for (int i = 0; i < 2; ++i) {
        float2 ev;
        ev.x = __builtin_amdgcn_exp2f(acc[i].x * NEG2L2E);
        ev.y = __builtin_amdgcn_exp2f(acc[i].y * NEG2L2E);
        *(float2*)(eb + (long)(2 * py + i) * TT + 2 * qx) = ev;
        colp.x += ev.x; colp.y += ev.y;
    }
    __syncthreads();                 // all reads of PA done before reuse
    float* scr = (float*)&PA[0];
    *(float2*)&scr[py * 64 + 2 * qx] = make_float2(colp.x, colp.y);
    __syncthreads();
    if (t < 64) {
        float s = 0.f;
        #pragma unroll
        for (int r = 0; r < 16; ++r) s += scr[r * 64 + t];
        lpart[((long)b * 16 + pt) * TT + q0 + t] = s;
    }
}

// ============ P3: out[b,p,:] = sum_q (e[p,q]/l[q]) * qin[b,q,:] ============
// 32p x 32d tile, 256 thr (4 waves), 4p x 4d per-lane microtile; each wave
// owns a 16-kk quarter of every 64-k chunk (k-split), LDS reduce at end.
// B staged async [k][d]; A transpose-staged with linv[k] folded in.
__global__ __launch_bounds__(256) void out_kernel(
    const float* __restrict__ ebuf, const float* __restrict__ qin,
    const float* __restrict__ lpart, float* __restrict__ out)
{
    const int b = blockIdx.z, pt = blockIdx.y, dt = blockIdx.x;
    const int m0 = pt * 32, n0 = dt * 32;
    const int t    = threadIdx.x;       // 0..255
    const int wv   = t >> 6;            // wave 0..3 -> kk quarter
    const int lane = t & 63;
    const int pg   = lane >> 3;         // p = 4*pg + i
    const int dg   = lane & 7;          // d = 4*dg + j

    __shared__ __align__(16) float smem[4 * 32 * 36];   // 18.4 KB: staging / reduce scratch
    __shared__ float linv[TT];
    float* As = smem;                    // [64k][36] transposed, linv-scaled: 2304 f
    float* Bs = smem + 64 * 36;          // [64k][32d]: 2048 f

    #pragma unroll
    for (int s = 0; s < 2; ++s) {
        int qq = t + 256 * s;
        float sum = 0.f;
        #pragma unroll
        for (int pb = 0; pb < 16; ++pb) sum += lpart[((long)b * 16 + pb) * TT + qq];
        linv[qq] = __builtin_amdgcn_rcpf(sum);
    }
    __syncthreads();

    const float* Ab = ebuf + ((long)b * TT + m0) * TT;   // 32 p-rows x 512 k
    const float* Bb = qin + (long)b * TT * DD + n0;      // 512 k-rows x 32 d

    const int ar = t >> 3, ak4 = (t & 7) * 4;            // A: p-row ar, k-quads ak4, ak4+32

    v2f acc[4][2];
    #pragma unroll
    for (int i = 0; i < 4; ++i) { acc[i][0] = splat2(0.f); acc[i][1] = splat2(0.f); }

    for (int c = 0; c < 8; ++c) {
        const int k0 = c * 64;
        // stage B async: 2048 f = 2 f4/thread, layout [k][32d]
        #pragma unroll
        for (int s = 0; s < 2; ++s) {
            int f = t + 256 * s, kr = f >> 3, d4 = (f & 7) * 4;
            stage16(Bb + (long)(k0 + kr) * DD + d4, &Bs[f * 4]);
        }
        // stage A manual: read [p][k4], scale by linv, transpose-write [k][p]
        #pragma unroll
        for (int s = 0; s < 2; ++s) {
            int kq = ak4 + 32 * s;
            float4 a = *(const float4*)(Ab + (long)ar * TT + k0 + kq);
            float4 lv = *(const float4*)&linv[k0 + kq];
            As[(kq + 0) * 36 + ar] = a.x * lv.x;
            As[(kq + 1) * 36 + ar] = a.y * lv.y;
            As[(kq + 2) * 36 + ar] = a.z * lv.z;
            As[(kq + 3) * 36 + ar] = a.w * lv.w;
        }
        __syncthreads();
        // wave wv computes kk quarter [16*wv, 16*wv+16)
        const int kb = 16 * wv;
        #pragma unroll
        for (int u = 0; u < 16; ++u) {
            int kk = kb + u;
            float4 a = *(const float4*)&As[kk * 36 + 4 * pg];
            v2f b0 = *(const v2f*)&Bs[kk * 32 + 4 * dg];
            v2f b1 = *(const v2f*)&Bs[kk * 32 + 4 * dg + 2];
            acc[0][0] = pk_fma(splat2(a.x), b0, acc[0][0]);
            acc[0][1] = pk_fma(splat2(a.x), b1, acc[0][1]);
            acc[1][0] = pk_fma(splat2(a.y), b0, acc[1][0]);
            acc[1][1] = pk_fma(splat2(a.y), b1, acc[1][1]);
            acc[2][0] = pk_fma(splat2(a.z), b0, acc[2][0]);
            acc[2][1] = pk_fma(splat2(a.z), b1, acc[2][1]);
            acc[3][0] = pk_fma(splat2(a.w), b0, acc[3][0]);
            acc[3][1] = pk_fma(splat2(a.w), b1, acc[3][1]);
        }
        __syncthreads();
    }

    // cross-wave k reduction: scratch [w][32p][36]
    float* scr = smem;
    #pragma unroll
    for (int i = 0; i < 4; ++i) {
        *(v2f*)&scr[wv * 1152 + (4 * pg + i) * 36 + 4 * dg]     = acc[i][0];
        *(v2f*)&scr[wv * 1152 + (4 * pg + i) * 36 + 4 * dg + 2] = acc[i][1];
    }
    __syncthreads();
    {
        int pr = t >> 3, d0 = (t & 7) * 4;
        float4 s0 = *(const float4*)&scr[0 * 1152 + pr * 36 + d0];
        float4 s1 = *(const float4*)&scr[1 * 1152 + pr * 36 + d0];
        float4 s2 = *(const float4*)&scr[2 * 1152 + pr * 36 + d0];
        float4 s3 = *(const float4*)&scr[3 * 1152 + pr * 36 + d0];
        float4 v;
        v.x = (s0.x + s1.x) + (s2.x + s3.x);
        v.y = (s0.y + s1.y) + (s2.y + s3.y);
        v.z = (s0.z + s1.z) + (s2.z + s3.z);
        v.w = (s0.w + s1.w) + (s2.w + s3.w);
        *(float4*)(out + ((long)b * TT + m0 + pr) * DD + n0 + d0) = v;
    }
}

extern "C" void kernel_launch(void* const* d_in, const int* in_sizes, int n_in,
                              void* d_out, int out_size, void* d_ws, size_t ws_size,
                              hipStream_t stream) {
    const float* q  = (const float*)d_in[0];
    const float* p  = (const float*)d_in[1];
    const float* W0 = (const float*)d_in[2];
    const float* W1 = (const float*)d_in[3];
    const float* vc = (const float*)d_in[4];
    float* out = (float*)d_out;

    float* ws    = (float*)d_ws;
    float* expQ  = ws;                // [4][256][512]  e^{2*projQ}, [b][d][q]
    float* expP  = ws + 524288;       // [4][512][256]  e^{2*projP}, [b][p][d]
    float* ebuf  = ws + 1048576;      // [4][512][512]
    float* lpart = ws + 2097152;      // [4][16][512]

    proj_exp_kernel<<<dim3(512), 256, 0, stream>>>(q, p, W0, W1, expQ, expP);
    score_kernel<<<dim3(8, 16, NB), 512, 0, stream>>>(expP, expQ, vc, ebuf, lpart);
    out_kernel<<<dim3(8, 16, NB), 256, 0, stream>>>(ebuf, q, lpart, out);
}

// Round 8
// 118.364 us; speedup vs baseline: 1.6954x; 1.0456x over previous
//
#include <hip/hip_runtime.h>

#define NB 4
#define TT 512          // TQ = TP
#define DD 256
#define K2L2E    2.885390081777927f     // 2*log2(e): e^{2x} = 2^{K*x}
#define NEG2L2E (-2.885390081777927f)

#if defined(__has_builtin)
# if __has_builtin(__builtin_amdgcn_global_load_lds)
#  define HAS_GLL 1
# endif
#endif

typedef float v2f __attribute__((ext_vector_type(2)));

__device__ __forceinline__ v2f pk_fma(v2f a, v2f b, v2f c) {
#if defined(__has_builtin)
# if __has_builtin(__builtin_elementwise_fma)
    return __builtin_elementwise_fma(a, b, c);
# else
    v2f r; r.x = __builtin_fmaf(a.x, b.x, c.x); r.y = __builtin_fmaf(a.y, b.y, c.y); return r;
# endif
#else
    v2f r; r.x = __builtin_fmaf(a.x, b.x, c.x); r.y = __builtin_fmaf(a.y, b.y, c.y); return r;
#endif
}
__device__ __forceinline__ v2f splat2(float s) { v2f r; r.x = s; r.y = s; return r; }

__device__ __forceinline__ void stage16(const float* __restrict__ g, float* l) {
#ifdef HAS_GLL
    __builtin_amdgcn_global_load_lds((const __attribute__((address_space(1))) void*)g,
                                     (__attribute__((address_space(3))) void*)l, 16, 0, 0);
#else
    *(float4*)l = *(const float4*)g;
#endif
}

// ============ P1: projections + exp epilogue ============
// expQ[b][d][q] = e^{2*(q@W0)[q,d]}  (TRANSPOSED, q-minor)
// expP[b][p][d] = e^{2*(p@W1)[p,d]}  (NATURAL, d-minor)
__global__ __launch_bounds__(256) void proj_exp_kernel(
    const float* __restrict__ qin, const float* __restrict__ pin,
    const float* __restrict__ W0, const float* __restrict__ W1,
    float* __restrict__ expQ, float* __restrict__ expP)
{
    const int blk = blockIdx.x;
    const int wh = blk >> 8, tid = blk & 255;
    const int m0 = (tid >> 2) * 32, n0 = (tid & 3) * 64;
    const float* A = wh ? pin : qin;
    const float* W = wh ? W1 : W0;

    __shared__ __align__(16) float As[32 * 34];   // [k][m]
    __shared__ __align__(16) float Bs[32 * 64];   // [k][n]

    const int t  = threadIdx.x;
    const int ar = t >> 3, ac4 = (t & 7) * 4;
    const int br = t >> 4, bc4 = (t & 15) * 4;
    // microtile index roles swap per output orientation (store-coalescing)
    const int tm = wh ? (t >> 4) : (t & 15);
    const int tn = wh ? (t & 15) : (t >> 4);

    const float* Ap = A + (long)(m0 + ar) * DD + ac4;

    float4 av  = *(const float4*)Ap;
    float4 bv0 = *(const float4*)(W + (long)br * DD + n0 + bc4);
    float4 bv1 = *(const float4*)(W + (long)(br + 16) * DD + n0 + bc4);

    v2f accv[2][2];
    accv[0][0] = splat2(0.f); accv[0][1] = splat2(0.f);
    accv[1][0] = splat2(0.f); accv[1][1] = splat2(0.f);

    for (int c = 0; c < 8; ++c) {
        As[(ac4 + 0) * 34 + ar] = av.x;
        As[(ac4 + 1) * 34 + ar] = av.y;
        As[(ac4 + 2) * 34 + ar] = av.z;
        As[(ac4 + 3) * 34 + ar] = av.w;
        *(float4*)&Bs[br * 64 + bc4]        = bv0;
        *(float4*)&Bs[(br + 16) * 64 + bc4] = bv1;
        __syncthreads();
        if (c < 7) {
            int k1 = (c + 1) * 32;
            av  = *(const float4*)(Ap + k1);
            bv0 = *(const float4*)(W + (long)(k1 + br) * DD + n0 + bc4);
            bv1 = *(const float4*)(W + (long)(k1 + 16 + br) * DD + n0 + bc4);
        }
        #pragma unroll
        for (int kk = 0; kk < 32; ++kk) {
            float2 a = *(const float2*)&As[kk * 34 + 2 * tm];
            float4 b = *(const float4*)&Bs[kk * 64 + 4 * tn];
            v2f b01; b01.x = b.x; b01.y = b.y;
            v2f b23; b23.x = b.z; b23.y = b.w;
            accv[0][0] = pk_fma(splat2(a.x), b01, accv[0][0]);
            accv[0][1] = pk_fma(splat2(a.x), b23, accv[0][1]);
            accv[1][0] = pk_fma(splat2(a.y), b01, accv[1][0]);
            accv[1][1] = pk_fma(splat2(a.y), b23, accv[1][1]);
        }
        __syncthreads();
    }

    float acc[2][4];
    #pragma unroll
    for (int i = 0; i < 2; ++i) {
        acc[i][0] = accv[i][0].x; acc[i][1] = accv[i][0].y;
        acc[i][2] = accv[i][1].x; acc[i][3] = accv[i][1].y;
    }

    const int bi = m0 >> 9;
    const int ml = m0 & 511;
    if (wh) {
        // natural: expP[bi][ml+2tm+i][n0+4tn .. +3], float4 store, tn-minor lanes
        #pragma unroll
        for (int i = 0; i < 2; ++i) {
            float4 st;
            st.x = __builtin_amdgcn_exp2f(acc[i][0] * K2L2E);
            st.y = __builtin_amdgcn_exp2f(acc[i][1] * K2L2E);
            st.z = __builtin_amdgcn_exp2f(acc[i][2] * K2L2E);
            st.w = __builtin_amdgcn_exp2f(acc[i][3] * K2L2E);
            *(float4*)(expP + ((long)bi * TT + ml + 2 * tm + i) * DD + n0 + 4 * tn) = st;
        }
    } else {
        // transposed: expQ[bi][n0+4tn+j][ml+2tm .. +1], float2 store, tm-minor lanes
        #pragma unroll
        for (int j = 0; j < 4; ++j) {
            int d = n0 + 4 * tn + j;
            float2 st;
            st.x = __builtin_amdgcn_exp2f(acc[0][j] * K2L2E);
            st.y = __builtin_amdgcn_exp2f(acc[1][j] * K2L2E);
            *(float2*)(expQ + ((long)bi * DD + d) * TT + ml + 2 * tm) = st;
        }
    }
}

// ============ P2: scores ============
// 32p x 64q tile, 512 thr, 2p x 2q-pk microtile, d-quad rcp batching with
// fused f = 1+E = pk_fma(a, B, 1):
//   sum v_k/f_k = (n01*t23 + n23*t01) * rcp(t01*t23),  n01 = v0*f1 + v1*f0
// 14 pk + 2 rcp per (i, d-quad). Two 128-d chunks, no dbuf, 49.4 KB LDS.
__global__ __launch_bounds__(512, 6) void score_kernel(
    const float* __restrict__ expP, const float* __restrict__ expQ,
    const float* __restrict__ vc, float* __restrict__ ebuf, float* __restrict__ lpart)
{
    const int b = blockIdx.z, pt = blockIdx.y, qt = blockIdx.x;
    const int p0 = pt * 32, q0 = qt * 64;
    const int t  = threadIdx.x;
    const int qx = t & 31, py = t >> 5;          // q = q0+2qx+{0,1}, p = p0+2py+{0,1}

    __shared__ __align__(16) float PA[32 * 128];   // [p][d-chunk] 16 KB
    __shared__ __align__(16) float QB[128 * 64];   // [d][q] 32 KB
    __shared__ __align__(16) float vcs[DD];

    const float* gP = expP + ((long)b * TT + p0) * DD;   // natural [p][d]
    const float* gQ = expQ + (long)b * DD * TT + q0;     // [d][q]

    // ---- stage chunk 0 (d = 0..127)
    #pragma unroll
    for (int s = 0; s < 2; ++s) {
        int f = t + 512 * s, pr = f >> 5, d4 = (f & 31) * 4;
        stage16(gP + (long)pr * DD + d4, &PA[f * 4]);
    }
    #pragma unroll
    for (int s = 0; s < 4; ++s) {
        int f = t + 512 * s, d = f >> 4, o4 = (f & 15) * 4;
        stage16(gQ + (long)d * TT + o4, &QB[f * 4]);
    }
    if (t < DD) vcs[t] = vc[t];
    __syncthreads();

    v2f acc[2]; acc[0] = splat2(0.f); acc[1] = splat2(0.f);
    const v2f one = splat2(1.0f);

    for (int c = 0; c < 2; ++c) {
        if (c == 1) {
            __syncthreads();   // chunk 0 fully consumed
            #pragma unroll
            for (int s = 0; s < 2; ++s) {
                int f = t + 512 * s, pr = f >> 5, d4 = (f & 31) * 4;
                stage16(gP + (long)pr * DD + 128 + d4, &PA[f * 4]);
            }
            #pragma unroll
            for (int s = 0; s < 4; ++s) {
                int f = t + 512 * s, d = f >> 4, o4 = (f & 15) * 4;
                stage16(gQ + (long)(128 + d) * TT + o4, &QB[f * 4]);
            }
            __syncthreads();   // drain staging
        }
        const float* vcb = &vcs[c * 128];
        #pragma unroll 4
        for (int dq = 0; dq < 32; ++dq) {
            float4 vq = *(const float4*)&vcb[4 * dq];
            float4 aq0 = *(const float4*)&PA[(2 * py) * 128 + 4 * dq];
            float4 aq1 = *(const float4*)&PA[(2 * py + 1) * 128 + 4 * dq];
            v2f B0 = *(const v2f*)&QB[(4 * dq + 0) * 64 + 2 * qx];
            v2f B1 = *(const v2f*)&QB[(4 * dq + 1) * 64 + 2 * qx];
            v2f B2 = *(const v2f*)&QB[(4 * dq + 2) * 64 + 2 * qx];
            v2f B3 = *(const v2f*)&QB[(4 * dq + 3) * 64 + 2 * qx];
            #pragma unroll
            for (int i = 0; i < 2; ++i) {
                float4 a = i ? aq1 : aq0;
                v2f f0 = pk_fma(splat2(a.x), B0, one);   // 1+E0
                v2f f1 = pk_fma(splat2(a.y), B1, one);
                v2f f2 = pk_fma(splat2(a.z), B2, one);
                v2f f3 = pk_fma(splat2(a.w), B3, one);
                v2f t01 = f0 * f1;
                v2f t23 = f2 * f3;
                v2f den = t01 * t23;
                v2f n01 = pk_fma(splat2(vq.x), f1, splat2(vq.y) * f0);
                v2f n23 = pk_fma(splat2(vq.z), f3, splat2(vq.w) * f2);
                v2f num = pk_fma(n01, t23, n23 * t01);
                v2f r;
                r.x = __builtin_amdgcn_rcpf(den.x);
                r.y = __builtin_amdgcn_rcpf(den.y);
                acc[i] = pk_fma(num, r, acc[i]);
            }
        }
    }

    // e = exp2(NEG2L2E * acc); write + per-block column partial sums
    float* eb = ebuf + ((long)b * TT + p0) * TT + q0;
    v2f colp = splat2(0.f);
    #pragma unroll
    for (int i = 0; i < 2; ++i) {
        float2 ev;
        ev.x = __builtin_amdgcn_exp2f(acc[i].x * NEG2L2E);
        ev.y = __builtin_amdgcn_exp2f(acc[i].y * NEG2L2E);
        *(float2*)(eb + (long)(2 * py + i) * TT + 2 * qx) = ev;
        colp.x += ev.x; colp.y += ev.y;
    }
    __syncthreads();                 // all reads of PA done before reuse
    float* scr = (float*)&PA[0];
    *(float2*)&scr[py * 64 + 2 * qx] = make_float2(colp.x, colp.y);
    __syncthreads();
    if (t < 64) {
        float s = 0.f;
        #pragma unroll
        for (int r = 0; r < 16; ++r) s += scr[r * 64 + t];
        lpart[((long)b * 16 + pt) * TT + q0 + t] = s;
    }
}

// ============ P3: out[b,p,:] = sum_q (e[p,q]/l[q]) * qin[b,q,:] ============
// 32p x 32d tile, 256 thr (4 waves), 4p x 4d per-lane microtile; each wave
// owns a 16-kk quarter of every 64-k chunk (k-split), LDS reduce at end.
// B staged async [k][d]; A transpose-staged with linv[k] folded in.
__global__ __launch_bounds__(256) void out_kernel(
    const float* __restrict__ ebuf, const float* __restrict__ qin,
    const float* __restrict__ lpart, float* __restrict__ out)
{
    const int b = blockIdx.z, pt = blockIdx.y, dt = blockIdx.x;
    const int m0 = pt * 32, n0 = dt * 32;
    const int t    = threadIdx.x;       // 0..255
    const int wv   = t >> 6;            // wave 0..3 -> kk quarter
    const int lane = t & 63;
    const int pg   = lane >> 3;         // p = 4*pg + i
    const int dg   = lane & 7;          // d = 4*dg + j

    __shared__ __align__(16) float smem[4 * 32 * 36];   // 18.4 KB: staging / reduce scratch
    __shared__ float linv[TT];
    float* As = smem;                    // [64k][36] transposed, linv-scaled
    float* Bs = smem + 64 * 36;          // [64k][32d]

    #pragma unroll
    for (int s = 0; s < 2; ++s) {
        int qq = t + 256 * s;
        float sum = 0.f;
        #pragma unroll
        for (int pb = 0; pb < 16; ++pb) sum += lpart[((long)b * 16 + pb) * TT + qq];
        linv[qq] = __builtin_amdgcn_rcpf(sum);
    }
    __syncthreads();

    const float* Ab = ebuf + ((long)b * TT + m0) * TT;   // 32 p-rows x 512 k
    const float* Bb = qin + (long)b * TT * DD + n0;      // 512 k-rows x 32 d

    const int ar = t >> 3, ak4 = (t & 7) * 4;            // A: p-row ar, k-quads ak4, ak4+32

    v2f acc[4][2];
    #pragma unroll
    for (int i = 0; i < 4; ++i) { acc[i][0] = splat2(0.f); acc[i][1] = splat2(0.f); }

    for (int c = 0; c < 8; ++c) {
        const int k0 = c * 64;
        // stage B async: 2048 f = 2 f4/thread, layout [k][32d]
        #pragma unroll
        for (int s = 0; s < 2; ++s) {
            int f = t + 256 * s, kr = f >> 3, d4 = (f & 7) * 4;
            stage16(Bb + (long)(k0 + kr) * DD + d4, &Bs[f * 4]);
        }
        // stage A manual: read [p][k4], scale by linv, transpose-write [k][p]
        #pragma unroll
        for (int s = 0; s < 2; ++s) {
            int kq = ak4 + 32 * s;
            float4 a = *(const float4*)(Ab + (long)ar * TT + k0 + kq);
            float4 lv = *(const float4*)&linv[k0 + kq];
            As[(kq + 0) * 36 + ar] = a.x * lv.x;
            As[(kq + 1) * 36 + ar] = a.y * lv.y;
            As[(kq + 2) * 36 + ar] = a.z * lv.z;
            As[(kq + 3) * 36 + ar] = a.w * lv.w;
        }
        __syncthreads();
        // wave wv computes kk quarter [16*wv, 16*wv+16)
        const int kb = 16 * wv;
        #pragma unroll
        for (int u = 0; u < 16; ++u) {
            int kk = kb + u;
            float4 a  = *(const float4*)&As[kk * 36 + 4 * pg];
            float4 bq = *(const float4*)&Bs[kk * 32 + 4 * dg];
            v2f b0; b0.x = bq.x; b0.y = bq.y;
            v2f b1; b1.x = bq.z; b1.y = bq.w;
            acc[0][0] = pk_fma(splat2(a.x), b0, acc[0][0]);
            acc[0][1] = pk_fma(splat2(a.x), b1, acc[0][1]);
            acc[1][0] = pk_fma(splat2(a.y), b0, acc[1][0]);
            acc[1][1] = pk_fma(splat2(a.y), b1, acc[1][1]);
            acc[2][0] = pk_fma(splat2(a.z), b0, acc[2][0]);
            acc[2][1] = pk_fma(splat2(a.z), b1, acc[2][1]);
            acc[3][0] = pk_fma(splat2(a.w), b0, acc[3][0]);
            acc[3][1] = pk_fma(splat2(a.w), b1, acc[3][1]);
        }
        __syncthreads();
    }

    // cross-wave k reduction: scratch [w][32p][36]
    float* scr = smem;
    #pragma unroll
    for (int i = 0; i < 4; ++i) {
        *(v2f*)&scr[wv * 1152 + (4 * pg + i) * 36 + 4 * dg]     = acc[i][0];
        *(v2f*)&scr[wv * 1152 + (4 * pg + i) * 36 + 4 * dg + 2] = acc[i][1];
    }
    __syncthreads();
    {
        int pr = t >> 3, d0 = (t & 7) * 4;
        float4 s0 = *(const float4*)&scr[0 * 1152 + pr * 36 + d0];
        float4 s1 = *(const float4*)&scr[1 * 1152 + pr * 36 + d0];
        float4 s2 = *(const float4*)&scr[2 * 1152 + pr * 36 + d0];
        float4 s3 = *(const float4*)&scr[3 * 1152 + pr * 36 + d0];
        float4 v;
        v.x = (s0.x + s1.x) + (s2.x + s3.x);
        v.y = (s0.y + s1.y) + (s2.y + s3.y);
        v.z = (s0.z + s1.z) + (s2.z + s3.z);
        v.w = (s0.w + s1.w) + (s2.w + s3.w);
        *(float4*)(out + ((long)b * TT + m0 + pr) * DD + n0 + d0) = v;
    }
}

extern "C" void kernel_launch(void* const* d_in, const int* in_sizes, int n_in,
                              void* d_out, int out_size, void* d_ws, size_t ws_size,
                              hipStream_t stream) {
    const float* q  = (const float*)d_in[0];
    const float* p  = (const float*)d_in[1];
    const float* W0 = (const float*)d_in[2];
    const float* W1 = (const float*)d_in[3];
    const float* vc = (const float*)d_in[4];
    float* out = (float*)d_out;

    float* ws    = (float*)d_ws;
    float* expQ  = ws;                // [4][256][512]  e^{2*projQ}, [b][d][q]
    float* expP  = ws + 524288;       // [4][512][256]  e^{2*projP}, [b][p][d]
    float* ebuf  = ws + 1048576;      // [4][512][512]
    float* lpart = ws + 2097152;      // [4][16][512]

    proj_exp_kernel<<<dim3(512), 256, 0, stream>>>(q, p, W0, W1, expQ, expP);
    score_kernel<<<dim3(8, 16, NB), 512, 0, stream>>>(expP, expQ, vc, ebuf, lpart);
    out_kernel<<<dim3(8, 16, NB), 256, 0, stream>>>(ebuf, q, lpart, out);
}